// Round 4
// baseline (2760.487 us; speedup 1.0000x reference)
//
#include <hip/hip_runtime.h>
#include <stdint.h>

// Problem constants
#define B_   128
#define T_   256
#define H_   256
#define E_   300
#define G4_  1024   // 4*H

typedef __attribute__((ext_vector_type(8))) short bf16x8s;  // 8 bf16 (4 VGPRs)
typedef __attribute__((ext_vector_type(4))) float f32x4;

__device__ __forceinline__ short f2bf(float f) {
    unsigned u = __builtin_bit_cast(unsigned, f);
    unsigned r = (u + 0x7fffu + ((u >> 16) & 1u)) >> 16;   // RNE
    return (short)r;
}
__device__ __forceinline__ float sigm(float x) { return 1.f / (1.f + __expf(-x)); }
__device__ __forceinline__ float ftanh(float x) {
    float e = __expf(-2.f * x);
    return (1.f - e) / (1.f + e);
}

// ---------------- prep: mask dtype detection + mask/rowtok build ----------------
__global__ void k_detect(const unsigned char* __restrict__ m8, int* __restrict__ flag) {
    int i = blockIdx.x * 256 + threadIdx.x;      // 0..32767
    if ((i & 3) != 0 && m8[i] != 0) atomicOr(flag, 1);   // nonzero off-aligned byte => 1-byte bool layout
}

__global__ void k_prep(const void* __restrict__ mask, const int* __restrict__ tokens,
                       const int* __restrict__ flag, float* __restrict__ maskf,
                       int* __restrict__ rowtok) {
    int i = blockIdx.x * 256 + threadIdx.x;      // i = b*T + t
    int isbyte = *flag;
    int mv = isbyte ? (int)((const unsigned char*)mask)[i] : ((const int*)mask)[i];
    maskf[i] = mv ? 1.f : 0.f;                   // [b][t]
    int b = i >> 8, t = i & 255;
    rowtok[t * B_ + b] = tokens[i];              // row r = t*B + b  -> token
}

// ---------------- Wh -> packed bf16 MFMA B-fragments ----------------
// frag(nt, ks): lane l, elem i  = Wh[ks*32 + (l>>4)*8 + i][nt*16 + (l&15)]
// stored at whp[((nt*8+ks)*64 + l)*8 + i]
__global__ void k_whpack(const float* __restrict__ Wh, short* __restrict__ whp) {
    int frag = blockIdx.x;              // 0..511 = nt*8+ks
    int nt = frag >> 3, ks = frag & 7;
    int l = threadIdx.x;
    int col = nt * 16 + (l & 15);
    int k0 = ks * 32 + (l >> 4) * 8;
    short tmp[8];
#pragma unroll
    for (int i = 0; i < 8; ++i) tmp[i] = f2bf(Wh[(size_t)(k0 + i) * G4_ + col]);
    int4 v;
    __builtin_memcpy(&v, tmp, 16);
    ((int4*)whp)[frag * 64 + l] = v;
}

// ---------------- generic fp32 tiled GEMM: C = (A@B + bias) * scale ----------------
template<bool GATHER>
__global__ __launch_bounds__(256) void k_gemm(
    const float* __restrict__ A, const float* __restrict__ Bm,
    const float* __restrict__ bias, float* __restrict__ C,
    int M, int N, int K, const int* __restrict__ rowidx, float scale)
{
    __shared__ __align__(16) float As[16][68];   // [k][m]
    __shared__ __align__(16) float Bs[16][68];   // [k][n]
    const int tid = threadIdx.x;
    const int tx = tid & 15, ty = tid >> 4;
    const int m0 = blockIdx.y * 64, n0 = blockIdx.x * 64;
    float acc[4][4] = {};

    int arow[4];
#pragma unroll
    for (int i = 0; i < 4; ++i) {
        int e = tid + i * 256;
        int ar = e >> 4;
        int r = m0 + ar;
        arow[i] = GATHER ? rowidx[r] : r;
    }

    for (int k0 = 0; k0 < K; k0 += 16) {
#pragma unroll
        for (int i = 0; i < 4; ++i) {
            int e = tid + i * 256;
            int ak = e & 15, ar = e >> 4;
            float vv = 0.f;
            if (k0 + ak < K) vv = A[(size_t)arow[i] * K + k0 + ak];
            As[ak][ar] = vv;
        }
#pragma unroll
        for (int i = 0; i < 4; ++i) {
            int e = tid + i * 256;
            int nc = e & 63, kr = e >> 6;
            float vv = 0.f;
            if (k0 + kr < K) vv = Bm[(size_t)(k0 + kr) * N + n0 + nc];
            Bs[kr][nc] = vv;
        }
        __syncthreads();
#pragma unroll
        for (int kk = 0; kk < 16; ++kk) {
            float4 av = *(const float4*)&As[kk][ty * 4];
            float4 bv = *(const float4*)&Bs[kk][tx * 4];
            float a_[4] = {av.x, av.y, av.z, av.w};
            float b_[4] = {bv.x, bv.y, bv.z, bv.w};
#pragma unroll
            for (int i = 0; i < 4; ++i)
#pragma unroll
                for (int j = 0; j < 4; ++j)
                    acc[i][j] = fmaf(a_[i], b_[j], acc[i][j]);
        }
        __syncthreads();
    }

    float bs_[4] = {0.f, 0.f, 0.f, 0.f};
    if (bias) {
#pragma unroll
        for (int j = 0; j < 4; ++j) bs_[j] = bias[n0 + tx * 4 + j];
    }
#pragma unroll
    for (int i = 0; i < 4; ++i) {
        float4 o;
        o.x = (acc[i][0] + bs_[0]) * scale;
        o.y = (acc[i][1] + bs_[1]) * scale;
        o.z = (acc[i][2] + bs_[2]) * scale;
        o.w = (acc[i][3] + bs_[3]) * scale;
        *(float4*)&C[(size_t)(m0 + ty * 4 + i) * N + n0 + tx * 4] = o;
    }
}

// ---------------- MFMA LSTM: 8 blocks x 16 batch rows, bf16 ----------------
// Wh residency: ks 0-1 in LDS (128 KB), ks 2-5 in VGPRs (256/wave), ks 6-7 L2-streamed.
// Wave w owns h-units [64w, 64w+64): n-tiles {16g + 4w + m} for g,m in 0..3.
#define LDA_H 264   // padded row stride (bf16 elems) for h LDS buffer

__global__ __launch_bounds__(256, 1) void lstm_mfma(
    const float* __restrict__ xW, const short* __restrict__ whp,
    float* __restrict__ hs)
{
    __shared__ __align__(16) short whc[128 * 64 * 8];     // ks 0..1 cached (128 KB)
    __shared__ __align__(16) short hb[2][16 * LDA_H];     // double-buffered h (bf16)
    const int tid = threadIdx.x;
    const int l = tid & 63;
    const int w = tid >> 6;            // wave 0..3
    const int cl = l & 15;             // A-row (batch) for reads / D-col within tile
    const int rowq = l >> 4;           // batch quad for D rows
    const int col0 = 64 * w;
    const int bbase = blockIdx.x * 16;

    // preload LDS frag cache: frags (nt, ks<2)
    for (int e = tid; e < 128 * 64; e += 256) {       // int4 units
        int frag = e >> 6, q = e & 63;                // frag = nt*2+ks
        int nt = frag >> 1, ks = frag & 1;
        ((int4*)whc)[e] = ((const int4*)whp)[(nt * 8 + ks) * 64 + q];
    }
    for (int e = tid; e < 2 * 16 * LDA_H; e += 256) ((short*)hb)[e] = 0;

    // persistent register-resident weights: ks 2..5 for this wave's 16 n-tiles
    bf16x8s wreg[4][4][4];   // [m][g][ks-2] — statically indexed (fully unrolled)
#pragma unroll
    for (int m = 0; m < 4; ++m)
#pragma unroll
        for (int g = 0; g < 4; ++g)
#pragma unroll
            for (int kr = 0; kr < 4; ++kr) {
                const int nt = 16 * g + 4 * w + m;
                wreg[m][g][kr] = *(const bf16x8s*)&whp[((size_t)(nt * 8 + 2 + kr) * 64 + l) * 8];
            }

    float creg[4][4];
#pragma unroll
    for (int m = 0; m < 4; ++m)
#pragma unroll
        for (int r = 0; r < 4; ++r) creg[m][r] = 0.f;
    __syncthreads();

    for (int t = 0; t < T_; ++t) {
        const short* hbr = hb[t & 1];
        short* hbw = hb[(t + 1) & 1];
        // A-fragments: a[ks] = h[cl][ks*32 + rowq*8 .. +7]
        bf16x8s a[8];
#pragma unroll
        for (int ks = 0; ks < 8; ++ks)
            a[ks] = *(const bf16x8s*)&hbr[cl * LDA_H + ks * 32 + rowq * 8];

        // y accumulators init from xW (issued early; 16 independent chains hide latency)
        const float* xwt = xW + ((size_t)t * B_ + bbase) * G4_;
        f32x4 y[4][4];
#pragma unroll
        for (int m = 0; m < 4; ++m)
#pragma unroll
            for (int g = 0; g < 4; ++g) {
                const int col = g * 256 + col0 + m * 16 + cl;
#pragma unroll
                for (int r = 0; r < 4; ++r)
                    y[m][g][r] = xwt[(size_t)(rowq * 4 + r) * G4_ + col];
            }

#pragma unroll
        for (int m = 0; m < 4; ++m) {
#pragma unroll
            for (int g = 0; g < 4; ++g) {
                const int nt = 16 * g + 4 * w + m;
                // streamed ks 6,7 (L2) — issue first, consume last
                bf16x8s s6 = *(const bf16x8s*)&whp[((size_t)(nt * 8 + 6) * 64 + l) * 8];
                bf16x8s s7 = *(const bf16x8s*)&whp[((size_t)(nt * 8 + 7) * 64 + l) * 8];
                // register-resident ks 2..5 first (no memory dependency)
                y[m][g] = __builtin_amdgcn_mfma_f32_16x16x32_bf16(a[2], wreg[m][g][0], y[m][g], 0, 0, 0);
                y[m][g] = __builtin_amdgcn_mfma_f32_16x16x32_bf16(a[3], wreg[m][g][1], y[m][g], 0, 0, 0);
                y[m][g] = __builtin_amdgcn_mfma_f32_16x16x32_bf16(a[4], wreg[m][g][2], y[m][g], 0, 0, 0);
                y[m][g] = __builtin_amdgcn_mfma_f32_16x16x32_bf16(a[5], wreg[m][g][3], y[m][g], 0, 0, 0);
                // LDS-cached ks 0,1
                bf16x8s c0 = *(const bf16x8s*)&whc[((nt * 2 + 0) * 64 + l) * 8];
                bf16x8s c1 = *(const bf16x8s*)&whc[((nt * 2 + 1) * 64 + l) * 8];
                y[m][g] = __builtin_amdgcn_mfma_f32_16x16x32_bf16(a[0], c0, y[m][g], 0, 0, 0);
                y[m][g] = __builtin_amdgcn_mfma_f32_16x16x32_bf16(a[1], c1, y[m][g], 0, 0, 0);
                // streamed ks 6,7
                y[m][g] = __builtin_amdgcn_mfma_f32_16x16x32_bf16(a[6], s6, y[m][g], 0, 0, 0);
                y[m][g] = __builtin_amdgcn_mfma_f32_16x16x32_bf16(a[7], s7, y[m][g], 0, 0, 0);
            }
        }

        // activations + c/h update
#pragma unroll
        for (int m = 0; m < 4; ++m) {
            const int j = col0 + m * 16 + cl;
#pragma unroll
            for (int r = 0; r < 4; ++r) {
                float iv = sigm(y[m][0][r]);
                float fv = sigm(y[m][1][r]);
                float gv = ftanh(y[m][2][r]);
                float ov = sigm(y[m][3][r]);
                float c = fmaf(fv, creg[m][r], iv * gv);
                creg[m][r] = c;
                float hv = ov * ftanh(c);
                int b = rowq * 4 + r;
                hbw[b * LDA_H + j] = f2bf(hv);
                hs[((size_t)(bbase + b) * T_ + t) * H_ + j] = hv;
            }
        }
        __syncthreads();
    }
}

// ---------------- flash-style single-head attention ----------------
__global__ __launch_bounds__(256) void k_attn(
    const float* __restrict__ q, const float* __restrict__ kk_,
    const float* __restrict__ v, const float* __restrict__ maskf,
    float* __restrict__ o)
{
    __shared__ __align__(16) float Qs[16][260];
    __shared__ __align__(16) float Ks[16][260];
    __shared__ __align__(16) float Vs[16][260];
    __shared__ float Ss[16][16];
    const int tid = threadIdx.x;
    const int tx = tid & 15, ty = tid >> 4;
    const int b = blockIdx.y, q0 = blockIdx.x * 16;
    const size_t base = (size_t)b * T_ * H_;

    for (int e4 = tid; e4 < 1024; e4 += 256) {
        int r = e4 >> 6, dq = e4 & 63;
        *(float4*)&Qs[r][dq * 4] = *(const float4*)&q[base + (size_t)(q0 + r) * H_ + dq * 4];
    }
    const float mrow = maskf[b * T_ + q0 + ty];
    float m = -1e30f, l = 0.f;
    float acc[16];
#pragma unroll
    for (int i = 0; i < 16; ++i) acc[i] = 0.f;

    for (int kt = 0; kt < 16; ++kt) {
        for (int e4 = tid; e4 < 1024; e4 += 256) {
            int r = e4 >> 6, dq = e4 & 63;
            *(float4*)&Ks[r][dq * 4] = *(const float4*)&kk_[base + (size_t)(kt * 16 + r) * H_ + dq * 4];
            *(float4*)&Vs[r][dq * 4] = *(const float4*)&v  [base + (size_t)(kt * 16 + r) * H_ + dq * 4];
        }
        __syncthreads();
        float s = 0.f;
#pragma unroll 16
        for (int d = 0; d < 256; d += 4) {
            float4 qv = *(const float4*)&Qs[ty][d];
            float4 kv = *(const float4*)&Ks[tx][d];
            s = fmaf(qv.x, kv.x, fmaf(qv.y, kv.y, fmaf(qv.z, kv.z, fmaf(qv.w, kv.w, s))));
        }
        if (mrow == 0.f) s = 0.f;   // masked query row -> uniform softmax
        Ss[ty][tx] = s;
        __syncthreads();
        float tmax = -1e30f;
#pragma unroll
        for (int x = 0; x < 16; ++x) tmax = fmaxf(tmax, Ss[ty][x]);
        float mnew = fmaxf(m, tmax);
        float rsc = __expf(m - mnew);
        float wv[16], wsum = 0.f;
#pragma unroll
        for (int x = 0; x < 16; ++x) { wv[x] = __expf(Ss[ty][x] - mnew); wsum += wv[x]; }
        l = l * rsc + wsum; m = mnew;
#pragma unroll
        for (int dd = 0; dd < 16; ++dd) acc[dd] *= rsc;
#pragma unroll
        for (int x = 0; x < 16; ++x) {
            float wx = wv[x];
#pragma unroll
            for (int dd = 0; dd < 16; ++dd)
                acc[dd] = fmaf(wx, Vs[x][tx + dd * 16], acc[dd]);
        }
        __syncthreads();
    }
    float inv = 1.f / l;
#pragma unroll
    for (int dd = 0; dd < 16; ++dd)
        o[base + (size_t)(q0 + ty) * H_ + tx + dd * 16] = acc[dd] * inv;
}

// ---------------- FC1 split-K partials ----------------
__global__ __launch_bounds__(256) void k_fc1(
    const float* __restrict__ flat, const float* __restrict__ W1, float* __restrict__ part)
{
    __shared__ __align__(16) float Wt[100][260];
    __shared__ __align__(16) float fs[2][256];
    const int kc = blockIdx.x, tid = threadIdx.x;
    for (int e = tid; e < 25600; e += 256) {
        int k = e / 100, j = e - k * 100;
        Wt[j][k] = W1[(size_t)(kc * 256 + k) * 100 + j];
    }
    __syncthreads();
    const int bh = tid / 100, j = tid - bh * 100;
    for (int bb = 0; bb < 64; ++bb) {
        for (int e = tid; e < 512; e += 256) {
            int bi = e >> 8, k = e & 255;
            fs[bi][k] = flat[(size_t)(bb * 2 + bi) * 65536 + kc * 256 + k];
        }
        __syncthreads();
        if (bh < 2) {
            float acc = 0.f;
#pragma unroll 16
            for (int k = 0; k < 256; k += 4) {
                float4 fv = *(const float4*)&fs[bh][k];
                float4 wv = *(const float4*)&Wt[j][k];
                acc = fmaf(fv.x, wv.x, fmaf(fv.y, wv.y, fmaf(fv.z, wv.z, fmaf(fv.w, wv.w, acc))));
            }
            part[(size_t)kc * 12800 + (bb * 2 + bh) * 100 + j] = acc;
        }
        __syncthreads();
    }
}

// ---------------- head ----------------
__global__ __launch_bounds__(128) void k_head(
    const float* __restrict__ part, const float* __restrict__ b1,
    const float* __restrict__ W2, const float* __restrict__ b2, float* __restrict__ out)
{
    __shared__ float h1s[100];
    __shared__ float ls[2];
    const int b = blockIdx.x, tid = threadIdx.x;
    if (tid < 100) {
        float s = 0.f;
        for (int kc = 0; kc < 256; ++kc) s += part[(size_t)kc * 12800 + b * 100 + tid];
        s += b1[tid];
        h1s[tid] = fmaxf(s, 0.f);
    }
    __syncthreads();
    if (tid < 2) {
        float lg = b2[tid];
        for (int j = 0; j < 100; ++j) lg = fmaf(h1s[j], W2[j * 2 + tid], lg);
        ls[tid] = lg;
    }
    __syncthreads();
    if (tid == 0) {
        float mm = fmaxf(ls[0], ls[1]);
        float e0 = __expf(ls[0] - mm), e1 = __expf(ls[1] - mm);
        float inv = 1.f / (e0 + e1);
        out[b * 2 + 0] = e0 * inv;
        out[b * 2 + 1] = e1 * inv;
    }
}

// ---------------- launch ----------------
extern "C" void kernel_launch(void* const* d_in, const int* in_sizes, int n_in,
                              void* d_out, int out_size, void* d_ws, size_t ws_size,
                              hipStream_t stream) {
    (void)in_sizes; (void)n_in; (void)out_size; (void)ws_size;
    const int*   tokens = (const int*)  d_in[0];
    const void*  mask   =               d_in[1];
    const float* emb    = (const float*)d_in[2];
    const float* Wi     = (const float*)d_in[3];
    const float* Wh     = (const float*)d_in[4];
    const float* b_lstm = (const float*)d_in[5];
    const float* Wq     = (const float*)d_in[6];
    const float* bq     = (const float*)d_in[7];
    const float* Wk     = (const float*)d_in[8];
    const float* bk     = (const float*)d_in[9];
    const float* Wv     = (const float*)d_in[10];
    const float* bv     = (const float*)d_in[11];
    const float* Wo     = (const float*)d_in[12];
    const float* bo     = (const float*)d_in[13];
    const float* W1     = (const float*)d_in[14];
    const float* b1     = (const float*)d_in[15];
    const float* W2     = (const float*)d_in[16];
    const float* b2     = (const float*)d_in[17];
    float* out = (float*)d_out;

    float* ws = (float*)d_ws;
    float* xw    = ws;                        // 33,554,432 f  [T][B][1024]
    float* hsb   = xw + 33554432;             //  8,388,608 f  [B][T][H]
    float* maskf = hsb + 8388608;             //     32,768 f
    int*   rowtok= (int*)(maskf + 32768);     //     32,768 i
    int*   flag  = rowtok + 32768;            //          1 i
    short* whp   = (short*)((((uintptr_t)(flag + 1)) + 255) & ~(uintptr_t)255);  // 262,144 bf16
    // region reuse inside xw after LSTM:
    float* qb   = xw;                         // q
    float* kb   = xw + 8388608;               // k  (later: fc1 partials)
    float* vb   = xw + 16777216;              // v
    float* proj = xw + 25165824;              // attn @ Wo  (= "flat")
    float* attn = hsb;                        // attention output overwrites hs
    float* part = kb;

    // prep
    hipMemsetAsync(flag, 0, sizeof(int), stream);
    k_detect<<<128, 256, 0, stream>>>((const unsigned char*)mask, flag);
    k_prep<<<128, 256, 0, stream>>>(mask, tokens, flag, maskf, rowtok);
    k_whpack<<<512, 64, 0, stream>>>(Wh, whp);

    // xW = gather(emb, tokens) @ Wi + b_lstm     (M=32768, K=300, N=1024)
    k_gemm<true><<<dim3(16, 512), 256, 0, stream>>>(emb, Wi, b_lstm, xw,
                                                    32768, 1024, 300, rowtok, 1.f);

    // LSTM — MFMA, 8 blocks x 16 batch rows, register-resident Wh
    lstm_mfma<<<8, 256, 0, stream>>>(xw, whp, hsb);

    // q,k,v projections (q scaled by 1/sqrt(H)=1/16 after bias)
    k_gemm<false><<<dim3(4, 512), 256, 0, stream>>>(hsb, Wq, bq, qb, 32768, 256, 256, nullptr, 0.0625f);
    k_gemm<false><<<dim3(4, 512), 256, 0, stream>>>(hsb, Wk, bk, kb, 32768, 256, 256, nullptr, 1.f);
    k_gemm<false><<<dim3(4, 512), 256, 0, stream>>>(hsb, Wv, bv, vb, 32768, 256, 256, nullptr, 1.f);

    // attention (writes over hs)
    k_attn<<<dim3(16, 128), 256, 0, stream>>>(qb, kb, vb, maskf, attn);

    // output projection: proj = attn @ Wo + bo
    k_gemm<false><<<dim3(4, 512), 256, 0, stream>>>(attn, Wo, bo, proj, 32768, 256, 256, nullptr, 1.f);

    // FC1 split-K partials + head
    k_fc1<<<256, 256, 0, stream>>>(proj, W1, part);
    k_head<<<128, 128, 0, stream>>>(part, b1, W2, b2, out);
}

// Round 5
// 2482.329 us; speedup vs baseline: 1.1121x; 1.1121x over previous
//
#include <hip/hip_runtime.h>
#include <stdint.h>

// Problem constants
#define B_   128
#define T_   256
#define H_   256
#define E_   300
#define G4_  1024   // 4*H

typedef __attribute__((ext_vector_type(8))) short bf16x8s;  // 8 bf16 (4 VGPRs)
typedef __attribute__((ext_vector_type(4))) float f32x4;

__device__ __forceinline__ short f2bf(float f) {
    unsigned u = __builtin_bit_cast(unsigned, f);
    unsigned r = (u + 0x7fffu + ((u >> 16) & 1u)) >> 16;   // RNE
    return (short)r;
}
__device__ __forceinline__ float sigm(float x) { return 1.f / (1.f + __expf(-x)); }
__device__ __forceinline__ float ftanh(float x) {
    float e = __expf(-2.f * x);
    return (1.f - e) / (1.f + e);
}

// ---------------- prep: mask dtype detection + mask/rowtok build ----------------
__global__ void k_detect(const unsigned char* __restrict__ m8, int* __restrict__ flag) {
    int i = blockIdx.x * 256 + threadIdx.x;      // 0..32767
    if ((i & 3) != 0 && m8[i] != 0) atomicOr(flag, 1);   // nonzero off-aligned byte => 1-byte bool layout
}

__global__ void k_prep(const void* __restrict__ mask, const int* __restrict__ tokens,
                       const int* __restrict__ flag, float* __restrict__ maskf,
                       int* __restrict__ rowtok) {
    int i = blockIdx.x * 256 + threadIdx.x;      // i = b*T + t
    int isbyte = *flag;
    int mv = isbyte ? (int)((const unsigned char*)mask)[i] : ((const int*)mask)[i];
    maskf[i] = mv ? 1.f : 0.f;                   // [b][t]
    int b = i >> 8, t = i & 255;
    rowtok[t * B_ + b] = tokens[i];              // row r = t*B + b  -> token
}

// ---------------- Wh -> packed bf16 MFMA B-fragments ----------------
// frag(nt, ks): lane l, elem i  = Wh[ks*32 + (l>>4)*8 + i][nt*16 + (l&15)]
// stored at whp[((nt*8+ks)*64 + l)*8 + i]
__global__ void k_whpack(const float* __restrict__ Wh, short* __restrict__ whp) {
    int frag = blockIdx.x;              // 0..511 = nt*8+ks
    int nt = frag >> 3, ks = frag & 7;
    int l = threadIdx.x;
    int col = nt * 16 + (l & 15);
    int k0 = ks * 32 + (l >> 4) * 8;
    short tmp[8];
#pragma unroll
    for (int i = 0; i < 8; ++i) tmp[i] = f2bf(Wh[(size_t)(k0 + i) * G4_ + col]);
    int4 v;
    __builtin_memcpy(&v, tmp, 16);
    ((int4*)whp)[frag * 64 + l] = v;
}

// ---------------- generic fp32 tiled GEMM: C = (A@B + bias) * scale ----------------
template<bool GATHER>
__global__ __launch_bounds__(256) void k_gemm(
    const float* __restrict__ A, const float* __restrict__ Bm,
    const float* __restrict__ bias, float* __restrict__ C,
    int M, int N, int K, const int* __restrict__ rowidx, float scale)
{
    __shared__ __align__(16) float As[16][68];   // [k][m]
    __shared__ __align__(16) float Bs[16][68];   // [k][n]
    const int tid = threadIdx.x;
    const int tx = tid & 15, ty = tid >> 4;
    const int m0 = blockIdx.y * 64, n0 = blockIdx.x * 64;
    float acc[4][4] = {};

    int arow[4];
#pragma unroll
    for (int i = 0; i < 4; ++i) {
        int e = tid + i * 256;
        int ar = e >> 4;
        int r = m0 + ar;
        arow[i] = GATHER ? rowidx[r] : r;
    }

    for (int k0 = 0; k0 < K; k0 += 16) {
#pragma unroll
        for (int i = 0; i < 4; ++i) {
            int e = tid + i * 256;
            int ak = e & 15, ar = e >> 4;
            float vv = 0.f;
            if (k0 + ak < K) vv = A[(size_t)arow[i] * K + k0 + ak];
            As[ak][ar] = vv;
        }
#pragma unroll
        for (int i = 0; i < 4; ++i) {
            int e = tid + i * 256;
            int nc = e & 63, kr = e >> 6;
            float vv = 0.f;
            if (k0 + kr < K) vv = Bm[(size_t)(k0 + kr) * N + n0 + nc];
            Bs[kr][nc] = vv;
        }
        __syncthreads();
#pragma unroll
        for (int kk = 0; kk < 16; ++kk) {
            float4 av = *(const float4*)&As[kk][ty * 4];
            float4 bv = *(const float4*)&Bs[kk][tx * 4];
            float a_[4] = {av.x, av.y, av.z, av.w};
            float b_[4] = {bv.x, bv.y, bv.z, bv.w};
#pragma unroll
            for (int i = 0; i < 4; ++i)
#pragma unroll
                for (int j = 0; j < 4; ++j)
                    acc[i][j] = fmaf(a_[i], b_[j], acc[i][j]);
        }
        __syncthreads();
    }

    float bs_[4] = {0.f, 0.f, 0.f, 0.f};
    if (bias) {
#pragma unroll
        for (int j = 0; j < 4; ++j) bs_[j] = bias[n0 + tx * 4 + j];
    }
#pragma unroll
    for (int i = 0; i < 4; ++i) {
        float4 o;
        o.x = (acc[i][0] + bs_[0]) * scale;
        o.y = (acc[i][1] + bs_[1]) * scale;
        o.z = (acc[i][2] + bs_[2]) * scale;
        o.w = (acc[i][3] + bs_[3]) * scale;
        *(float4*)&C[(size_t)(m0 + ty * 4 + i) * N + n0 + tx * 4] = o;
    }
}

// ---------------- MFMA LSTM: 8 blocks x 16 batch rows, 16 waves (4/SIMD) ----------------
// Wave w owns hidden units [16w, 16w+16): n-tiles {g*16 + w}, g = gate 0..3.
// Wh residency: ks 0-1 in LDS (128 KB), ks 2-7 streamed from L2 (whp resident per XCD).
#define LDA_H 264   // padded row stride (bf16 elems) for h LDS buffer

__global__ __launch_bounds__(1024, 1) void lstm_mfma(
    const float* __restrict__ xW, const short* __restrict__ whp,
    float* __restrict__ hs)
{
    __shared__ __align__(16) short whc[128 * 64 * 8];     // frags (nt, ks<2): 128 KB
    __shared__ __align__(16) short hb[2][16 * LDA_H];     // double-buffered h (bf16)
    const int tid = threadIdx.x;
    const int l = tid & 63;
    const int w = tid >> 6;            // wave 0..15
    const int cl = l & 15;             // A-row (batch) for reads / D-col within tile
    const int rowq = l >> 4;           // batch quad for D rows
    const int bbase = blockIdx.x * 16;
    const int j = w * 16 + cl;         // hidden unit owned by this lane

    // preload LDS frag cache: frags (nt, ks<2)
    for (int e = tid; e < 128 * 64; e += 1024) {       // int4 units
        int frag = e >> 6, q = e & 63;                 // frag = nt*2+ks
        int nt = frag >> 1, ks = frag & 1;
        ((int4*)whc)[e] = ((const int4*)whp)[(nt * 8 + ks) * 64 + q];
    }
    for (int e = tid; e < 2 * 16 * LDA_H; e += 1024) ((short*)hb)[e] = 0;
    float creg[4] = {0.f, 0.f, 0.f, 0.f};
    __syncthreads();

    for (int t = 0; t < T_; ++t) {
        const short* hbr = hb[t & 1];
        short* hbw = hb[(t + 1) & 1];
        // A-fragments (shared across gates): a[ks] = h[cl][ks*32 + rowq*8 .. +7]
        bf16x8s a[8];
#pragma unroll
        for (int ks = 0; ks < 8; ++ks)
            a[ks] = *(const bf16x8s*)&hbr[cl * LDA_H + ks * 32 + rowq * 8];

        // y accumulators init from xW
        const float* xwt = xW + ((size_t)t * B_ + bbase) * G4_;
        f32x4 y[4];
#pragma unroll
        for (int g = 0; g < 4; ++g) {
            const int col = g * 256 + j;
#pragma unroll
            for (int r = 0; r < 4; ++r)
                y[g][r] = xwt[(size_t)(rowq * 4 + r) * G4_ + col];
        }

#pragma unroll
        for (int g = 0; g < 4; ++g) {
            const int nt = g * 16 + w;
            const size_t sb = ((size_t)nt * 8 * 64 + l) * 8;   // frag(nt, 0) lane base
            // streamed ks 2..7 (L2-resident per XCD) — issue early
            bf16x8s s2 = *(const bf16x8s*)&whp[sb + 2 * 64 * 8];
            bf16x8s s3 = *(const bf16x8s*)&whp[sb + 3 * 64 * 8];
            bf16x8s s4 = *(const bf16x8s*)&whp[sb + 4 * 64 * 8];
            bf16x8s s5 = *(const bf16x8s*)&whp[sb + 5 * 64 * 8];
            bf16x8s s6 = *(const bf16x8s*)&whp[sb + 6 * 64 * 8];
            bf16x8s s7 = *(const bf16x8s*)&whp[sb + 7 * 64 * 8];
            // LDS-cached ks 0,1
            bf16x8s c0 = *(const bf16x8s*)&whc[((nt * 2 + 0) * 64 + l) * 8];
            bf16x8s c1 = *(const bf16x8s*)&whc[((nt * 2 + 1) * 64 + l) * 8];
            y[g] = __builtin_amdgcn_mfma_f32_16x16x32_bf16(a[0], c0, y[g], 0, 0, 0);
            y[g] = __builtin_amdgcn_mfma_f32_16x16x32_bf16(a[1], c1, y[g], 0, 0, 0);
            y[g] = __builtin_amdgcn_mfma_f32_16x16x32_bf16(a[2], s2, y[g], 0, 0, 0);
            y[g] = __builtin_amdgcn_mfma_f32_16x16x32_bf16(a[3], s3, y[g], 0, 0, 0);
            y[g] = __builtin_amdgcn_mfma_f32_16x16x32_bf16(a[4], s4, y[g], 0, 0, 0);
            y[g] = __builtin_amdgcn_mfma_f32_16x16x32_bf16(a[5], s5, y[g], 0, 0, 0);
            y[g] = __builtin_amdgcn_mfma_f32_16x16x32_bf16(a[6], s6, y[g], 0, 0, 0);
            y[g] = __builtin_amdgcn_mfma_f32_16x16x32_bf16(a[7], s7, y[g], 0, 0, 0);
        }

        // activations + c/h update (lane: 4 batch rows x 1 hidden unit)
#pragma unroll
        for (int r = 0; r < 4; ++r) {
            float iv = sigm(y[0][r]);
            float fv = sigm(y[1][r]);
            float gv = ftanh(y[2][r]);
            float ov = sigm(y[3][r]);
            float c = fmaf(fv, creg[r], iv * gv);
            creg[r] = c;
            float hv = ov * ftanh(c);
            int b = rowq * 4 + r;
            hbw[b * LDA_H + j] = f2bf(hv);
            hs[((size_t)(bbase + b) * T_ + t) * H_ + j] = hv;
        }
        __syncthreads();
    }
}

// ---------------- flash-style single-head attention ----------------
__global__ __launch_bounds__(256) void k_attn(
    const float* __restrict__ q, const float* __restrict__ kk_,
    const float* __restrict__ v, const float* __restrict__ maskf,
    float* __restrict__ o)
{
    __shared__ __align__(16) float Qs[16][260];
    __shared__ __align__(16) float Ks[16][260];
    __shared__ __align__(16) float Vs[16][260];
    __shared__ float Ss[16][16];
    const int tid = threadIdx.x;
    const int tx = tid & 15, ty = tid >> 4;
    const int b = blockIdx.y, q0 = blockIdx.x * 16;
    const size_t base = (size_t)b * T_ * H_;

    for (int e4 = tid; e4 < 1024; e4 += 256) {
        int r = e4 >> 6, dq = e4 & 63;
        *(float4*)&Qs[r][dq * 4] = *(const float4*)&q[base + (size_t)(q0 + r) * H_ + dq * 4];
    }
    const float mrow = maskf[b * T_ + q0 + ty];
    float m = -1e30f, l = 0.f;
    float acc[16];
#pragma unroll
    for (int i = 0; i < 16; ++i) acc[i] = 0.f;

    for (int kt = 0; kt < 16; ++kt) {
        for (int e4 = tid; e4 < 1024; e4 += 256) {
            int r = e4 >> 6, dq = e4 & 63;
            *(float4*)&Ks[r][dq * 4] = *(const float4*)&kk_[base + (size_t)(kt * 16 + r) * H_ + dq * 4];
            *(float4*)&Vs[r][dq * 4] = *(const float4*)&v  [base + (size_t)(kt * 16 + r) * H_ + dq * 4];
        }
        __syncthreads();
        float s = 0.f;
#pragma unroll 16
        for (int d = 0; d < 256; d += 4) {
            float4 qv = *(const float4*)&Qs[ty][d];
            float4 kv = *(const float4*)&Ks[tx][d];
            s = fmaf(qv.x, kv.x, fmaf(qv.y, kv.y, fmaf(qv.z, kv.z, fmaf(qv.w, kv.w, s))));
        }
        if (mrow == 0.f) s = 0.f;   // masked query row -> uniform softmax
        Ss[ty][tx] = s;
        __syncthreads();
        float tmax = -1e30f;
#pragma unroll
        for (int x = 0; x < 16; ++x) tmax = fmaxf(tmax, Ss[ty][x]);
        float mnew = fmaxf(m, tmax);
        float rsc = __expf(m - mnew);
        float wv[16], wsum = 0.f;
#pragma unroll
        for (int x = 0; x < 16; ++x) { wv[x] = __expf(Ss[ty][x] - mnew); wsum += wv[x]; }
        l = l * rsc + wsum; m = mnew;
#pragma unroll
        for (int dd = 0; dd < 16; ++dd) acc[dd] *= rsc;
#pragma unroll
        for (int x = 0; x < 16; ++x) {
            float wx = wv[x];
#pragma unroll
            for (int dd = 0; dd < 16; ++dd)
                acc[dd] = fmaf(wx, Vs[x][tx + dd * 16], acc[dd]);
        }
        __syncthreads();
    }
    float inv = 1.f / l;
#pragma unroll
    for (int dd = 0; dd < 16; ++dd)
        o[base + (size_t)(q0 + ty) * H_ + tx + dd * 16] = acc[dd] * inv;
}

// ---------------- FC1 split-K partials ----------------
__global__ __launch_bounds__(256) void k_fc1(
    const float* __restrict__ flat, const float* __restrict__ W1, float* __restrict__ part)
{
    __shared__ __align__(16) float Wt[100][260];
    __shared__ __align__(16) float fs[2][256];
    const int kc = blockIdx.x, tid = threadIdx.x;
    for (int e = tid; e < 25600; e += 256) {
        int k = e / 100, j = e - k * 100;
        Wt[j][k] = W1[(size_t)(kc * 256 + k) * 100 + j];
    }
    __syncthreads();
    const int bh = tid / 100, j = tid - bh * 100;
    for (int bb = 0; bb < 64; ++bb) {
        for (int e = tid; e < 512; e += 256) {
            int bi = e >> 8, k = e & 255;
            fs[bi][k] = flat[(size_t)(bb * 2 + bi) * 65536 + kc * 256 + k];
        }
        __syncthreads();
        if (bh < 2) {
            float acc = 0.f;
#pragma unroll 16
            for (int k = 0; k < 256; k += 4) {
                float4 fv = *(const float4*)&fs[bh][k];
                float4 wv = *(const float4*)&Wt[j][k];
                acc = fmaf(fv.x, wv.x, fmaf(fv.y, wv.y, fmaf(fv.z, wv.z, fmaf(fv.w, wv.w, acc))));
            }
            part[(size_t)kc * 12800 + (bb * 2 + bh) * 100 + j] = acc;
        }
        __syncthreads();
    }
}

// ---------------- head ----------------
__global__ __launch_bounds__(128) void k_head(
    const float* __restrict__ part, const float* __restrict__ b1,
    const float* __restrict__ W2, const float* __restrict__ b2, float* __restrict__ out)
{
    __shared__ float h1s[100];
    __shared__ float ls[2];
    const int b = blockIdx.x, tid = threadIdx.x;
    if (tid < 100) {
        float s = 0.f;
        for (int kc = 0; kc < 256; ++kc) s += part[(size_t)kc * 12800 + b * 100 + tid];
        s += b1[tid];
        h1s[tid] = fmaxf(s, 0.f);
    }
    __syncthreads();
    if (tid < 2) {
        float lg = b2[tid];
        for (int j = 0; j < 100; ++j) lg = fmaf(h1s[j], W2[j * 2 + tid], lg);
        ls[tid] = lg;
    }
    __syncthreads();
    if (tid == 0) {
        float mm = fmaxf(ls[0], ls[1]);
        float e0 = __expf(ls[0] - mm), e1 = __expf(ls[1] - mm);
        float inv = 1.f / (e0 + e1);
        out[b * 2 + 0] = e0 * inv;
        out[b * 2 + 1] = e1 * inv;
    }
}

// ---------------- launch ----------------
extern "C" void kernel_launch(void* const* d_in, const int* in_sizes, int n_in,
                              void* d_out, int out_size, void* d_ws, size_t ws_size,
                              hipStream_t stream) {
    (void)in_sizes; (void)n_in; (void)out_size; (void)ws_size;
    const int*   tokens = (const int*)  d_in[0];
    const void*  mask   =               d_in[1];
    const float* emb    = (const float*)d_in[2];
    const float* Wi     = (const float*)d_in[3];
    const float* Wh     = (const float*)d_in[4];
    const float* b_lstm = (const float*)d_in[5];
    const float* Wq     = (const float*)d_in[6];
    const float* bq     = (const float*)d_in[7];
    const float* Wk     = (const float*)d_in[8];
    const float* bk     = (const float*)d_in[9];
    const float* Wv     = (const float*)d_in[10];
    const float* bv     = (const float*)d_in[11];
    const float* Wo     = (const float*)d_in[12];
    const float* bo     = (const float*)d_in[13];
    const float* W1     = (const float*)d_in[14];
    const float* b1     = (const float*)d_in[15];
    const float* W2     = (const float*)d_in[16];
    const float* b2     = (const float*)d_in[17];
    float* out = (float*)d_out;

    float* ws = (float*)d_ws;
    float* xw    = ws;                        // 33,554,432 f  [T][B][1024]
    float* hsb   = xw + 33554432;             //  8,388,608 f  [B][T][H]
    float* maskf = hsb + 8388608;             //     32,768 f
    int*   rowtok= (int*)(maskf + 32768);     //     32,768 i
    int*   flag  = rowtok + 32768;            //          1 i
    short* whp   = (short*)((((uintptr_t)(flag + 1)) + 255) & ~(uintptr_t)255);  // 262,144 bf16
    // region reuse inside xw after LSTM:
    float* qb   = xw;                         // q
    float* kb   = xw + 8388608;               // k  (later: fc1 partials)
    float* vb   = xw + 16777216;              // v
    float* proj = xw + 25165824;              // attn @ Wo  (= "flat")
    float* attn = hsb;                        // attention output overwrites hs
    float* part = kb;

    // prep
    hipMemsetAsync(flag, 0, sizeof(int), stream);
    k_detect<<<128, 256, 0, stream>>>((const unsigned char*)mask, flag);
    k_prep<<<128, 256, 0, stream>>>(mask, tokens, flag, maskf, rowtok);
    k_whpack<<<512, 64, 0, stream>>>(Wh, whp);

    // xW = gather(emb, tokens) @ Wi + b_lstm     (M=32768, K=300, N=1024)
    k_gemm<true><<<dim3(16, 512), 256, 0, stream>>>(emb, Wi, b_lstm, xw,
                                                    32768, 1024, 300, rowtok, 1.f);

    // LSTM — MFMA, 8 blocks x 16 batch rows, 16 waves/block (4 per SIMD)
    lstm_mfma<<<8, 1024, 0, stream>>>(xw, whp, hsb);

    // q,k,v projections (q scaled by 1/sqrt(H)=1/16 after bias)
    k_gemm<false><<<dim3(4, 512), 256, 0, stream>>>(hsb, Wq, bq, qb, 32768, 256, 256, nullptr, 0.0625f);
    k_gemm<false><<<dim3(4, 512), 256, 0, stream>>>(hsb, Wk, bk, kb, 32768, 256, 256, nullptr, 1.f);
    k_gemm<false><<<dim3(4, 512), 256, 0, stream>>>(hsb, Wv, bv, vb, 32768, 256, 256, nullptr, 1.f);

    // attention (writes over hs)
    k_attn<<<dim3(16, 128), 256, 0, stream>>>(qb, kb, vb, maskf, attn);

    // output projection: proj = attn @ Wo + bo
    k_gemm<false><<<dim3(4, 512), 256, 0, stream>>>(attn, Wo, bo, proj, 32768, 256, 256, nullptr, 1.f);

    // FC1 split-K partials + head
    k_fc1<<<256, 256, 0, stream>>>(proj, W1, part);
    k_head<<<128, 128, 0, stream>>>(part, b1, W2, b2, out);
}

// Round 6
// 2301.926 us; speedup vs baseline: 1.1992x; 1.0784x over previous
//
#include <hip/hip_runtime.h>
#include <stdint.h>

// Problem constants
#define B_   128
#define T_   256
#define H_   256
#define E_   300
#define G4_  1024   // 4*H

typedef __attribute__((ext_vector_type(8))) short bf16x8s;  // 8 bf16 (4 VGPRs)
typedef __attribute__((ext_vector_type(4))) float f32x4;

__device__ __forceinline__ short f2bf(float f) {
    unsigned u = __builtin_bit_cast(unsigned, f);
    unsigned r = (u + 0x7fffu + ((u >> 16) & 1u)) >> 16;   // RNE
    return (short)r;
}
__device__ __forceinline__ float bf2f(short s) {
    unsigned u = (unsigned)(unsigned short)s;
    return __builtin_bit_cast(float, u << 16);
}
__device__ __forceinline__ float sigm(float x) { return 1.f / (1.f + __expf(-x)); }
__device__ __forceinline__ float ftanh(float x) {
    float e = __expf(-2.f * x);
    return (1.f - e) / (1.f + e);
}

// ---------------- prep: mask dtype detection + mask/rowtok build ----------------
__global__ void k_detect(const unsigned char* __restrict__ m8, int* __restrict__ flag) {
    int i = blockIdx.x * 256 + threadIdx.x;      // 0..32767
    if ((i & 3) != 0 && m8[i] != 0) atomicOr(flag, 1);   // nonzero off-aligned byte => 1-byte bool layout
}

__global__ void k_prep(const void* __restrict__ mask, const int* __restrict__ tokens,
                       const int* __restrict__ flag, float* __restrict__ maskf,
                       int* __restrict__ rowtok) {
    int i = blockIdx.x * 256 + threadIdx.x;      // i = b*T + t
    int isbyte = *flag;
    int mv = isbyte ? (int)((const unsigned char*)mask)[i] : ((const int*)mask)[i];
    maskf[i] = mv ? 1.f : 0.f;                   // [b][t]
    int b = i >> 8, t = i & 255;
    rowtok[t * B_ + b] = tokens[i];              // row r = t*B + b  -> token
}

// ---------------- Wh -> packed bf16 MFMA B-fragments ----------------
// frag(nt, ks): lane l, elem i  = Wh[ks*32 + (l>>4)*8 + i][nt*16 + (l&15)]
// stored at whp[((nt*8+ks)*64 + l)*8 + i]
__global__ void k_whpack(const float* __restrict__ Wh, short* __restrict__ whp) {
    int frag = blockIdx.x;              // 0..511 = nt*8+ks
    int nt = frag >> 3, ks = frag & 7;
    int l = threadIdx.x;
    int col = nt * 16 + (l & 15);
    int k0 = ks * 32 + (l >> 4) * 8;
    short tmp[8];
#pragma unroll
    for (int i = 0; i < 8; ++i) tmp[i] = f2bf(Wh[(size_t)(k0 + i) * G4_ + col]);
    int4 v;
    __builtin_memcpy(&v, tmp, 16);
    ((int4*)whp)[frag * 64 + l] = v;
}

// ---------------- generic fp32 tiled GEMM: C = (A@B + bias) * scale ----------------
// BF16OUT: write bf16 (short) instead of fp32
template<bool GATHER, bool BF16OUT>
__global__ __launch_bounds__(256) void k_gemm(
    const float* __restrict__ A, const float* __restrict__ Bm,
    const float* __restrict__ bias, void* __restrict__ Cv,
    int M, int N, int K, const int* __restrict__ rowidx, float scale)
{
    __shared__ __align__(16) float As[16][68];   // [k][m]
    __shared__ __align__(16) float Bs[16][68];   // [k][n]
    const int tid = threadIdx.x;
    const int tx = tid & 15, ty = tid >> 4;
    const int m0 = blockIdx.y * 64, n0 = blockIdx.x * 64;
    float acc[4][4] = {};

    int arow[4];
#pragma unroll
    for (int i = 0; i < 4; ++i) {
        int e = tid + i * 256;
        int ar = e >> 4;
        int r = m0 + ar;
        arow[i] = GATHER ? rowidx[r] : r;
    }

    for (int k0 = 0; k0 < K; k0 += 16) {
#pragma unroll
        for (int i = 0; i < 4; ++i) {
            int e = tid + i * 256;
            int ak = e & 15, ar = e >> 4;
            float vv = 0.f;
            if (k0 + ak < K) vv = A[(size_t)arow[i] * K + k0 + ak];
            As[ak][ar] = vv;
        }
#pragma unroll
        for (int i = 0; i < 4; ++i) {
            int e = tid + i * 256;
            int nc = e & 63, kr = e >> 6;
            float vv = 0.f;
            if (k0 + kr < K) vv = Bm[(size_t)(k0 + kr) * N + n0 + nc];
            Bs[kr][nc] = vv;
        }
        __syncthreads();
#pragma unroll
        for (int kk = 0; kk < 16; ++kk) {
            float4 av = *(const float4*)&As[kk][ty * 4];
            float4 bv = *(const float4*)&Bs[kk][tx * 4];
            float a_[4] = {av.x, av.y, av.z, av.w};
            float b_[4] = {bv.x, bv.y, bv.z, bv.w};
#pragma unroll
            for (int i = 0; i < 4; ++i)
#pragma unroll
                for (int j = 0; j < 4; ++j)
                    acc[i][j] = fmaf(a_[i], b_[j], acc[i][j]);
        }
        __syncthreads();
    }

    float bs_[4] = {0.f, 0.f, 0.f, 0.f};
    if (bias) {
#pragma unroll
        for (int j = 0; j < 4; ++j) bs_[j] = bias[n0 + tx * 4 + j];
    }
#pragma unroll
    for (int i = 0; i < 4; ++i) {
        float o0 = (acc[i][0] + bs_[0]) * scale;
        float o1 = (acc[i][1] + bs_[1]) * scale;
        float o2 = (acc[i][2] + bs_[2]) * scale;
        float o3 = (acc[i][3] + bs_[3]) * scale;
        size_t idx = (size_t)(m0 + ty * 4 + i) * N + n0 + tx * 4;
        if constexpr (BF16OUT) {
            short4 o; o.x = f2bf(o0); o.y = f2bf(o1); o.z = f2bf(o2); o.w = f2bf(o3);
            *(short4*)&((short*)Cv)[idx] = o;
        } else {
            float4 o; o.x = o0; o.y = o1; o.z = o2; o.w = o3;
            *(float4*)&((float*)Cv)[idx] = o;
        }
    }
}

// ---------------- MFMA LSTM: 8 blocks x 16 batch rows, 8 waves (2/SIMD) ----------------
// Wave w owns hidden units [32w, 32w+32): n-tiles {g*16 + 2w + p}, g=gate, p=0,1.
// Wh residency: ks2-5 in REGISTERS (128 VGPR/wave), ks0-1 in LDS (128 KB),
// ks6-7 streamed from L2 (128 KB/block/step). xW is bf16.
#define LDA_H 264   // padded row stride (bf16 elems) for h LDS buffer

__global__ __launch_bounds__(512, 2) void lstm_mfma(
    const short* __restrict__ xW, const short* __restrict__ whp,
    float* __restrict__ hs)
{
    __shared__ __align__(16) short whc[128 * 64 * 8];     // frags (nt, ks<2): 128 KB
    __shared__ __align__(16) short hb[2][16 * LDA_H];     // double-buffered h (bf16)
    const int tid = threadIdx.x;
    const int l = tid & 63;
    const int w = tid >> 6;            // wave 0..7
    const int cl = l & 15;             // A-row (batch) for reads / D-col within tile
    const int rowq = l >> 4;           // batch quad for D rows
    const int bbase = blockIdx.x * 16;

    // preload LDS frag cache: frags (nt, ks<2)
    for (int e = tid; e < 128 * 64; e += 512) {        // int4 units
        int frag = e >> 6, q = e & 63;                 // frag = nt*2+ks
        int nt = frag >> 1, ks = frag & 1;
        ((int4*)whc)[e] = ((const int4*)whp)[(nt * 8 + ks) * 64 + q];
    }
    for (int e = tid; e < 2 * 16 * LDA_H; e += 512) ((short*)hb)[e] = 0;

    // persistent register-resident weights: ks 2..5 for this wave's 8 n-tiles
    bf16x8s wreg[2][4][4];   // [p][g][ks-2] — statically indexed (fully unrolled)
#pragma unroll
    for (int p = 0; p < 2; ++p)
#pragma unroll
        for (int g = 0; g < 4; ++g)
#pragma unroll
            for (int kr = 0; kr < 4; ++kr) {
                const int nt = g * 16 + w * 2 + p;
                wreg[p][g][kr] = *(const bf16x8s*)&whp[((size_t)(nt * 8 + 2 + kr) * 64 + l) * 8];
            }

    float creg[2][4];
#pragma unroll
    for (int p = 0; p < 2; ++p)
#pragma unroll
        for (int r = 0; r < 4; ++r) creg[p][r] = 0.f;
    __syncthreads();

    for (int t = 0; t < T_; ++t) {
        const short* hbr = hb[t & 1];
        short* hbw = hb[(t + 1) & 1];
        // A-fragments (shared across all 8 n-tiles): a[ks] = h[cl][ks*32 + rowq*8 .. +7]
        bf16x8s a[8];
#pragma unroll
        for (int ks = 0; ks < 8; ++ks)
            a[ks] = *(const bf16x8s*)&hbr[cl * LDA_H + ks * 32 + rowq * 8];

        // y accumulators init from xW (bf16)
        const short* xwt = xW + ((size_t)t * B_ + bbase) * G4_;
        f32x4 y[2][4];
#pragma unroll
        for (int p = 0; p < 2; ++p)
#pragma unroll
            for (int g = 0; g < 4; ++g) {
                const int col = g * 256 + w * 32 + p * 16 + cl;
#pragma unroll
                for (int r = 0; r < 4; ++r)
                    y[p][g][r] = bf2f(xwt[(size_t)(rowq * 4 + r) * G4_ + col]);
            }

#pragma unroll
        for (int p = 0; p < 2; ++p) {
#pragma unroll
            for (int g = 0; g < 4; ++g) {
                const int nt = g * 16 + w * 2 + p;
                const size_t sb = ((size_t)nt * 8 * 64 + l) * 8;   // frag(nt,0) lane base
                // streamed ks 6,7 (L2) — issue first, consume last
                bf16x8s s6 = *(const bf16x8s*)&whp[sb + 6 * 64 * 8];
                bf16x8s s7 = *(const bf16x8s*)&whp[sb + 7 * 64 * 8];
                // LDS-cached ks 0,1
                bf16x8s c0 = *(const bf16x8s*)&whc[((nt * 2 + 0) * 64 + l) * 8];
                bf16x8s c1 = *(const bf16x8s*)&whc[((nt * 2 + 1) * 64 + l) * 8];
                // register-resident ks 2..5 first (no memory dependency)
                y[p][g] = __builtin_amdgcn_mfma_f32_16x16x32_bf16(a[2], wreg[p][g][0], y[p][g], 0, 0, 0);
                y[p][g] = __builtin_amdgcn_mfma_f32_16x16x32_bf16(a[3], wreg[p][g][1], y[p][g], 0, 0, 0);
                y[p][g] = __builtin_amdgcn_mfma_f32_16x16x32_bf16(a[4], wreg[p][g][2], y[p][g], 0, 0, 0);
                y[p][g] = __builtin_amdgcn_mfma_f32_16x16x32_bf16(a[5], wreg[p][g][3], y[p][g], 0, 0, 0);
                y[p][g] = __builtin_amdgcn_mfma_f32_16x16x32_bf16(a[0], c0, y[p][g], 0, 0, 0);
                y[p][g] = __builtin_amdgcn_mfma_f32_16x16x32_bf16(a[1], c1, y[p][g], 0, 0, 0);
                y[p][g] = __builtin_amdgcn_mfma_f32_16x16x32_bf16(a[6], s6, y[p][g], 0, 0, 0);
                y[p][g] = __builtin_amdgcn_mfma_f32_16x16x32_bf16(a[7], s7, y[p][g], 0, 0, 0);
            }
        }

        // activations + c/h update (lane: 4 batch rows x 2 hidden units)
#pragma unroll
        for (int p = 0; p < 2; ++p) {
            const int j = w * 32 + p * 16 + cl;
#pragma unroll
            for (int r = 0; r < 4; ++r) {
                float iv = sigm(y[p][0][r]);
                float fv = sigm(y[p][1][r]);
                float gv = ftanh(y[p][2][r]);
                float ov = sigm(y[p][3][r]);
                float c = fmaf(fv, creg[p][r], iv * gv);
                creg[p][r] = c;
                float hv = ov * ftanh(c);
                int b = rowq * 4 + r;
                hbw[b * LDA_H + j] = f2bf(hv);
                hs[((size_t)(bbase + b) * T_ + t) * H_ + j] = hv;
            }
        }
        __syncthreads();
    }
}

// ---------------- flash-style single-head attention ----------------
__global__ __launch_bounds__(256) void k_attn(
    const float* __restrict__ q, const float* __restrict__ kk_,
    const float* __restrict__ v, const float* __restrict__ maskf,
    float* __restrict__ o)
{
    __shared__ __align__(16) float Qs[16][260];
    __shared__ __align__(16) float Ks[16][260];
    __shared__ __align__(16) float Vs[16][260];
    __shared__ float Ss[16][16];
    const int tid = threadIdx.x;
    const int tx = tid & 15, ty = tid >> 4;
    const int b = blockIdx.y, q0 = blockIdx.x * 16;
    const size_t base = (size_t)b * T_ * H_;

    for (int e4 = tid; e4 < 1024; e4 += 256) {
        int r = e4 >> 6, dq = e4 & 63;
        *(float4*)&Qs[r][dq * 4] = *(const float4*)&q[base + (size_t)(q0 + r) * H_ + dq * 4];
    }
    const float mrow = maskf[b * T_ + q0 + ty];
    float m = -1e30f, l = 0.f;
    float acc[16];
#pragma unroll
    for (int i = 0; i < 16; ++i) acc[i] = 0.f;

    for (int kt = 0; kt < 16; ++kt) {
        for (int e4 = tid; e4 < 1024; e4 += 256) {
            int r = e4 >> 6, dq = e4 & 63;
            *(float4*)&Ks[r][dq * 4] = *(const float4*)&kk_[base + (size_t)(kt * 16 + r) * H_ + dq * 4];
            *(float4*)&Vs[r][dq * 4] = *(const float4*)&v  [base + (size_t)(kt * 16 + r) * H_ + dq * 4];
        }
        __syncthreads();
        float s = 0.f;
#pragma unroll 16
        for (int d = 0; d < 256; d += 4) {
            float4 qv = *(const float4*)&Qs[ty][d];
            float4 kv = *(const float4*)&Ks[tx][d];
            s = fmaf(qv.x, kv.x, fmaf(qv.y, kv.y, fmaf(qv.z, kv.z, fmaf(qv.w, kv.w, s))));
        }
        if (mrow == 0.f) s = 0.f;   // masked query row -> uniform softmax
        Ss[ty][tx] = s;
        __syncthreads();
        float tmax = -1e30f;
#pragma unroll
        for (int x = 0; x < 16; ++x) tmax = fmaxf(tmax, Ss[ty][x]);
        float mnew = fmaxf(m, tmax);
        float rsc = __expf(m - mnew);
        float wv[16], wsum = 0.f;
#pragma unroll
        for (int x = 0; x < 16; ++x) { wv[x] = __expf(Ss[ty][x] - mnew); wsum += wv[x]; }
        l = l * rsc + wsum; m = mnew;
#pragma unroll
        for (int dd = 0; dd < 16; ++dd) acc[dd] *= rsc;
#pragma unroll
        for (int x = 0; x < 16; ++x) {
            float wx = wv[x];
#pragma unroll
            for (int dd = 0; dd < 16; ++dd)
                acc[dd] = fmaf(wx, Vs[x][tx + dd * 16], acc[dd]);
        }
        __syncthreads();
    }
    float inv = 1.f / l;
#pragma unroll
    for (int dd = 0; dd < 16; ++dd)
        o[base + (size_t)(q0 + ty) * H_ + tx + dd * 16] = acc[dd] * inv;
}

// ---------------- FC1 split-K partials ----------------
__global__ __launch_bounds__(256) void k_fc1(
    const float* __restrict__ flat, const float* __restrict__ W1, float* __restrict__ part)
{
    __shared__ __align__(16) float Wt[100][260];
    __shared__ __align__(16) float fs[2][256];
    const int kc = blockIdx.x, tid = threadIdx.x;
    for (int e = tid; e < 25600; e += 256) {
        int k = e / 100, j = e - k * 100;
        Wt[j][k] = W1[(size_t)(kc * 256 + k) * 100 + j];
    }
    __syncthreads();
    const int bh = tid / 100, j = tid - bh * 100;
    for (int bb = 0; bb < 64; ++bb) {
        for (int e = tid; e < 512; e += 256) {
            int bi = e >> 8, k = e & 255;
            fs[bi][k] = flat[(size_t)(bb * 2 + bi) * 65536 + kc * 256 + k];
        }
        __syncthreads();
        if (bh < 2) {
            float acc = 0.f;
#pragma unroll 16
            for (int k = 0; k < 256; k += 4) {
                float4 fv = *(const float4*)&fs[bh][k];
                float4 wv = *(const float4*)&Wt[j][k];
                acc = fmaf(fv.x, wv.x, fmaf(fv.y, wv.y, fmaf(fv.z, wv.z, fmaf(fv.w, wv.w, acc))));
            }
            part[(size_t)kc * 12800 + (bb * 2 + bh) * 100 + j] = acc;
        }
        __syncthreads();
    }
}

// ---------------- head ----------------
__global__ __launch_bounds__(128) void k_head(
    const float* __restrict__ part, const float* __restrict__ b1,
    const float* __restrict__ W2, const float* __restrict__ b2, float* __restrict__ out)
{
    __shared__ float h1s[100];
    __shared__ float ls[2];
    const int b = blockIdx.x, tid = threadIdx.x;
    if (tid < 100) {
        float s = 0.f;
        for (int kc = 0; kc < 256; ++kc) s += part[(size_t)kc * 12800 + b * 100 + tid];
        s += b1[tid];
        h1s[tid] = fmaxf(s, 0.f);
    }
    __syncthreads();
    if (tid < 2) {
        float lg = b2[tid];
        for (int j = 0; j < 100; ++j) lg = fmaf(h1s[j], W2[j * 2 + tid], lg);
        ls[tid] = lg;
    }
    __syncthreads();
    if (tid == 0) {
        float mm = fmaxf(ls[0], ls[1]);
        float e0 = __expf(ls[0] - mm), e1 = __expf(ls[1] - mm);
        float inv = 1.f / (e0 + e1);
        out[b * 2 + 0] = e0 * inv;
        out[b * 2 + 1] = e1 * inv;
    }
}

// ---------------- launch ----------------
extern "C" void kernel_launch(void* const* d_in, const int* in_sizes, int n_in,
                              void* d_out, int out_size, void* d_ws, size_t ws_size,
                              hipStream_t stream) {
    (void)in_sizes; (void)n_in; (void)out_size; (void)ws_size;
    const int*   tokens = (const int*)  d_in[0];
    const void*  mask   =               d_in[1];
    const float* emb    = (const float*)d_in[2];
    const float* Wi     = (const float*)d_in[3];
    const float* Wh     = (const float*)d_in[4];
    const float* b_lstm = (const float*)d_in[5];
    const float* Wq     = (const float*)d_in[6];
    const float* bq     = (const float*)d_in[7];
    const float* Wk     = (const float*)d_in[8];
    const float* bk     = (const float*)d_in[9];
    const float* Wv     = (const float*)d_in[10];
    const float* bv     = (const float*)d_in[11];
    const float* Wo     = (const float*)d_in[12];
    const float* bo     = (const float*)d_in[13];
    const float* W1     = (const float*)d_in[14];
    const float* b1     = (const float*)d_in[15];
    const float* W2     = (const float*)d_in[16];
    const float* b2     = (const float*)d_in[17];
    float* out = (float*)d_out;

    float* ws = (float*)d_ws;
    float* reg0  = ws;                        // 33,554,432 f region (134 MB)
    short* xwb   = (short*)reg0;              // bf16 xW [T][B][1024] (67 MB, first half of reg0)
    float* hsb   = reg0 + 33554432;           //  8,388,608 f  [B][T][H]
    float* maskf = hsb + 8388608;             //     32,768 f
    int*   rowtok= (int*)(maskf + 32768);     //     32,768 i
    int*   flag  = rowtok + 32768;            //          1 i
    short* whp   = (short*)((((uintptr_t)(flag + 1)) + 255) & ~(uintptr_t)255);  // 262,144 bf16
    // region reuse inside reg0 after LSTM (xwb dead then):
    float* qb   = reg0;                       // q
    float* kb   = reg0 + 8388608;             // k  (later: fc1 partials)
    float* vb   = reg0 + 16777216;            // v
    float* proj = reg0 + 25165824;            // attn @ Wo  (= "flat")
    float* attn = hsb;                        // attention output overwrites hs
    float* part = kb;

    // prep
    hipMemsetAsync(flag, 0, sizeof(int), stream);
    k_detect<<<128, 256, 0, stream>>>((const unsigned char*)mask, flag);
    k_prep<<<128, 256, 0, stream>>>(mask, tokens, flag, maskf, rowtok);
    k_whpack<<<512, 64, 0, stream>>>(Wh, whp);

    // xW = gather(emb, tokens) @ Wi + b_lstm  -> bf16  (M=32768, K=300, N=1024)
    k_gemm<true, true><<<dim3(16, 512), 256, 0, stream>>>(emb, Wi, b_lstm, xwb,
                                                          32768, 1024, 300, rowtok, 1.f);

    // LSTM — MFMA, 8 blocks x 16 batch rows, 8 waves (2/SIMD), register-resident Wh
    lstm_mfma<<<8, 512, 0, stream>>>(xwb, whp, hsb);

    // q,k,v projections (q scaled by 1/sqrt(H)=1/16 after bias)
    k_gemm<false, false><<<dim3(4, 512), 256, 0, stream>>>(hsb, Wq, bq, qb, 32768, 256, 256, nullptr, 0.0625f);
    k_gemm<false, false><<<dim3(4, 512), 256, 0, stream>>>(hsb, Wk, bk, kb, 32768, 256, 256, nullptr, 1.f);
    k_gemm<false, false><<<dim3(4, 512), 256, 0, stream>>>(hsb, Wv, bv, vb, 32768, 256, 256, nullptr, 1.f);

    // attention (writes over hs)
    k_attn<<<dim3(16, 128), 256, 0, stream>>>(qb, kb, vb, maskf, attn);

    // output projection: proj = attn @ Wo + bo
    k_gemm<false, false><<<dim3(4, 512), 256, 0, stream>>>(attn, Wo, bo, proj, 32768, 256, 256, nullptr, 1.f);

    // FC1 split-K partials + head
    k_fc1<<<256, 256, 0, stream>>>(proj, W1, part);
    k_head<<<128, 128, 0, stream>>>(part, b1, W2, b2, out);
}

// Round 7
// 2192.144 us; speedup vs baseline: 1.2593x; 1.0501x over previous
//
#include <hip/hip_runtime.h>
#include <stdint.h>

// Problem constants
#define B_   128
#define T_   256
#define H_   256
#define E_   300
#define G4_  1024   // 4*H

typedef __attribute__((ext_vector_type(8))) short bf16x8s;  // 8 bf16 (4 VGPRs)
typedef __attribute__((ext_vector_type(4))) float f32x4;

__device__ __forceinline__ short f2bf(float f) {
    unsigned u = __builtin_bit_cast(unsigned, f);
    unsigned r = (u + 0x7fffu + ((u >> 16) & 1u)) >> 16;   // RNE
    return (short)r;
}
__device__ __forceinline__ float bf2f(short s) {
    unsigned u = (unsigned)(unsigned short)s;
    return __builtin_bit_cast(float, u << 16);
}
__device__ __forceinline__ float sigm(float x) { return 1.f / (1.f + __expf(-x)); }
__device__ __forceinline__ float ftanh(float x) {
    float e = __expf(-2.f * x);
    return (1.f - e) / (1.f + e);
}

// ---------------- prep: mask dtype detection + mask/rowtok build ----------------
__global__ void k_detect(const unsigned char* __restrict__ m8, int* __restrict__ flag) {
    int i = blockIdx.x * 256 + threadIdx.x;      // 0..32767
    if ((i & 3) != 0 && m8[i] != 0) atomicOr(flag, 1);   // nonzero off-aligned byte => 1-byte bool layout
}

__global__ void k_prep(const void* __restrict__ mask, const int* __restrict__ tokens,
                       const int* __restrict__ flag, float* __restrict__ maskf,
                       int* __restrict__ rowtok) {
    int i = blockIdx.x * 256 + threadIdx.x;      // i = b*T + t
    int isbyte = *flag;
    int mv = isbyte ? (int)((const unsigned char*)mask)[i] : ((const int*)mask)[i];
    maskf[i] = mv ? 1.f : 0.f;                   // [b][t]
    int b = i >> 8, t = i & 255;
    rowtok[t * B_ + b] = tokens[i];              // row r = t*B + b  -> token
}

// ---------------- generic W[KREAL][N] -> packed bf16 MFMA B-fragments ----------------
// frag(nt, ks): lane l, elem i = W[ks*32 + (l>>4)*8 + i][nt*16 + (l&15)]  (0 if k>=KREAL)
// stored at out[((nt*KS+ks)*64 + l)*8 + i];  grid = (N/16)*KS, 64 threads
__global__ void k_bpack(const float* __restrict__ W, short* __restrict__ out,
                        int N, int KS, int KREAL) {
    int frag = blockIdx.x;
    int nt = frag / KS, ks = frag - nt * KS;
    int l = threadIdx.x;
    int col = nt * 16 + (l & 15);
    int k0 = ks * 32 + (l >> 4) * 8;
    short tmp[8];
#pragma unroll
    for (int i = 0; i < 8; ++i) {
        int k = k0 + i;
        tmp[i] = (k < KREAL) ? f2bf(W[(size_t)k * N + col]) : (short)0;
    }
    int4 v;
    __builtin_memcpy(&v, tmp, 16);
    ((int4*)out)[(size_t)frag * 64 + l] = v;
}

// ---------------- bf16 MFMA GEMM: C = (A@B + bias) * scale ----------------
// A: MxKREAL row-major (fp32 or bf16, optionally row-gathered), staged to LDS bf16.
// Bp: packed frags (k_bpack layout). Block = 64 rows, 4 waves; wave w owns rows [16w,16w+16).
// N multiple of 256 handled in 256-col chunks. grid.x = M/64.
template<bool GATHER, bool ABF16, bool BF16OUT, int KS>
__global__ __launch_bounds__(256) void k_gemm_mfma(
    const void* __restrict__ Av, const short* __restrict__ Bp,
    const float* __restrict__ bias, void* __restrict__ Cv,
    int N, int KREAL, const int* __restrict__ rowidx, float scale)
{
    constexpr int KP = KS * 32;
    constexpr int LDA = KP + 8;      // +8 bf16 skew: cl*4-bank spread, 2-way max (free)
    __shared__ __align__(16) short As[64 * LDA];
    const int tid = threadIdx.x;
    const int l = tid & 63, w = tid >> 6;
    const int cl = l & 15, rowq = l >> 4;
    const int m0 = blockIdx.x * 64;

    // stage A tile (64 x KP) as bf16, zero-padded past KREAL
    for (int e = tid; e < 64 * KP; e += 256) {
        int r = e / KP, k = e - r * KP;
        int row = m0 + r;
        int arow = GATHER ? rowidx[row] : row;
        short sv = 0;
        if (k < KREAL) {
            if constexpr (ABF16) sv = ((const short*)Av)[(size_t)arow * KREAL + k];
            else                 sv = f2bf(((const float*)Av)[(size_t)arow * KREAL + k]);
        }
        As[r * LDA + k] = sv;
    }
    __syncthreads();

    // A-fragments for this wave's 16 rows (validated layout: row=cl, k=ks*32+rowq*8+i)
    bf16x8s a[KS];
#pragma unroll
    for (int ks = 0; ks < KS; ++ks)
        a[ks] = *(const bf16x8s*)&As[(w * 16 + cl) * LDA + ks * 32 + rowq * 8];

    const int nchunks = N >> 8;
    for (int ch = 0; ch < nchunks; ++ch) {
#pragma unroll
        for (int ntl = 0; ntl < 16; ++ntl) {
            const int nt = ch * 16 + ntl;
            const float bv = bias[nt * 16 + cl];
            f32x4 y = {bv, bv, bv, bv};
#pragma unroll
            for (int ks = 0; ks < KS; ++ks) {
                bf16x8s bf = *(const bf16x8s*)&Bp[((size_t)(nt * KS + ks) * 64 + l) * 8];
                y = __builtin_amdgcn_mfma_f32_16x16x32_bf16(a[ks], bf, y, 0, 0, 0);
            }
#pragma unroll
            for (int r = 0; r < 4; ++r) {
                size_t idx = (size_t)(m0 + w * 16 + rowq * 4 + r) * N + nt * 16 + cl;
                float ov = y[r] * scale;
                if constexpr (BF16OUT) ((short*)Cv)[idx] = f2bf(ov);
                else                   ((float*)Cv)[idx] = ov;
            }
        }
    }
}

// ---------------- MFMA LSTM: 8 blocks x 16 batch rows, 8 waves (2/SIMD) ----------------
// Wave w owns hidden units [32w, 32w+32): n-tiles {g*16 + 2w + p}, g=gate, p=0,1.
// Wh residency: ks2-5 in registers, ks0-1 in LDS (128 KB), ks6-7 streamed from L2.
// xW bf16; hs written bf16.
#define LDA_H 264   // padded row stride (bf16 elems) for h LDS buffer

__global__ __launch_bounds__(512, 2) void lstm_mfma(
    const short* __restrict__ xW, const short* __restrict__ whp,
    short* __restrict__ hs)
{
    __shared__ __align__(16) short whc[128 * 64 * 8];     // frags (nt, ks<2): 128 KB
    __shared__ __align__(16) short hb[2][16 * LDA_H];     // double-buffered h (bf16)
    const int tid = threadIdx.x;
    const int l = tid & 63;
    const int w = tid >> 6;            // wave 0..7
    const int cl = l & 15;
    const int rowq = l >> 4;
    const int bbase = blockIdx.x * 16;

    for (int e = tid; e < 128 * 64; e += 512) {        // int4 units
        int frag = e >> 6, q = e & 63;                 // frag = nt*2+ks
        int nt = frag >> 1, ks = frag & 1;
        ((int4*)whc)[e] = ((const int4*)whp)[(nt * 8 + ks) * 64 + q];
    }
    for (int e = tid; e < 2 * 16 * LDA_H; e += 512) ((short*)hb)[e] = 0;

    bf16x8s wreg[2][4][4];   // ks 2..5 for this wave's 8 n-tiles
#pragma unroll
    for (int p = 0; p < 2; ++p)
#pragma unroll
        for (int g = 0; g < 4; ++g)
#pragma unroll
            for (int kr = 0; kr < 4; ++kr) {
                const int nt = g * 16 + w * 2 + p;
                wreg[p][g][kr] = *(const bf16x8s*)&whp[((size_t)(nt * 8 + 2 + kr) * 64 + l) * 8];
            }

    float creg[2][4];
#pragma unroll
    for (int p = 0; p < 2; ++p)
#pragma unroll
        for (int r = 0; r < 4; ++r) creg[p][r] = 0.f;
    __syncthreads();

    for (int t = 0; t < T_; ++t) {
        const short* hbr = hb[t & 1];
        short* hbw = hb[(t + 1) & 1];
        bf16x8s a[8];
#pragma unroll
        for (int ks = 0; ks < 8; ++ks)
            a[ks] = *(const bf16x8s*)&hbr[cl * LDA_H + ks * 32 + rowq * 8];

        const short* xwt = xW + ((size_t)t * B_ + bbase) * G4_;
        f32x4 y[2][4];
#pragma unroll
        for (int p = 0; p < 2; ++p)
#pragma unroll
            for (int g = 0; g < 4; ++g) {
                const int col = g * 256 + w * 32 + p * 16 + cl;
#pragma unroll
                for (int r = 0; r < 4; ++r)
                    y[p][g][r] = bf2f(xwt[(size_t)(rowq * 4 + r) * G4_ + col]);
            }

#pragma unroll
        for (int p = 0; p < 2; ++p) {
#pragma unroll
            for (int g = 0; g < 4; ++g) {
                const int nt = g * 16 + w * 2 + p;
                const size_t sb = ((size_t)nt * 8 * 64 + l) * 8;
                bf16x8s s6 = *(const bf16x8s*)&whp[sb + 6 * 64 * 8];
                bf16x8s s7 = *(const bf16x8s*)&whp[sb + 7 * 64 * 8];
                bf16x8s c0 = *(const bf16x8s*)&whc[((nt * 2 + 0) * 64 + l) * 8];
                bf16x8s c1 = *(const bf16x8s*)&whc[((nt * 2 + 1) * 64 + l) * 8];
                y[p][g] = __builtin_amdgcn_mfma_f32_16x16x32_bf16(a[2], wreg[p][g][0], y[p][g], 0, 0, 0);
                y[p][g] = __builtin_amdgcn_mfma_f32_16x16x32_bf16(a[3], wreg[p][g][1], y[p][g], 0, 0, 0);
                y[p][g] = __builtin_amdgcn_mfma_f32_16x16x32_bf16(a[4], wreg[p][g][2], y[p][g], 0, 0, 0);
                y[p][g] = __builtin_amdgcn_mfma_f32_16x16x32_bf16(a[5], wreg[p][g][3], y[p][g], 0, 0, 0);
                y[p][g] = __builtin_amdgcn_mfma_f32_16x16x32_bf16(a[0], c0, y[p][g], 0, 0, 0);
                y[p][g] = __builtin_amdgcn_mfma_f32_16x16x32_bf16(a[1], c1, y[p][g], 0, 0, 0);
                y[p][g] = __builtin_amdgcn_mfma_f32_16x16x32_bf16(a[6], s6, y[p][g], 0, 0, 0);
                y[p][g] = __builtin_amdgcn_mfma_f32_16x16x32_bf16(a[7], s7, y[p][g], 0, 0, 0);
            }
        }

#pragma unroll
        for (int p = 0; p < 2; ++p) {
            const int j = w * 32 + p * 16 + cl;
#pragma unroll
            for (int r = 0; r < 4; ++r) {
                float iv = sigm(y[p][0][r]);
                float fv = sigm(y[p][1][r]);
                float gv = ftanh(y[p][2][r]);
                float ov = sigm(y[p][3][r]);
                float c = fmaf(fv, creg[p][r], iv * gv);
                creg[p][r] = c;
                float hv = ov * ftanh(c);
                short hvb = f2bf(hv);
                int b = rowq * 4 + r;
                hbw[b * LDA_H + j] = hvb;
                hs[((size_t)(bbase + b) * T_ + t) * H_ + j] = hvb;
            }
        }
        __syncthreads();
    }
}

// ---------------- flash-style single-head attention (fp32 q,k,v) ----------------
__global__ __launch_bounds__(256) void k_attn(
    const float* __restrict__ q, const float* __restrict__ kk_,
    const float* __restrict__ v, const float* __restrict__ maskf,
    float* __restrict__ o)
{
    __shared__ __align__(16) float Qs[16][260];
    __shared__ __align__(16) float Ks[16][260];
    __shared__ __align__(16) float Vs[16][260];
    __shared__ float Ss[16][16];
    const int tid = threadIdx.x;
    const int tx = tid & 15, ty = tid >> 4;
    const int b = blockIdx.y, q0 = blockIdx.x * 16;
    const size_t base = (size_t)b * T_ * H_;

    for (int e4 = tid; e4 < 1024; e4 += 256) {
        int r = e4 >> 6, dq = e4 & 63;
        *(float4*)&Qs[r][dq * 4] = *(const float4*)&q[base + (size_t)(q0 + r) * H_ + dq * 4];
    }
    const float mrow = maskf[b * T_ + q0 + ty];
    float m = -1e30f, l = 0.f;
    float acc[16];
#pragma unroll
    for (int i = 0; i < 16; ++i) acc[i] = 0.f;

    for (int kt = 0; kt < 16; ++kt) {
        for (int e4 = tid; e4 < 1024; e4 += 256) {
            int r = e4 >> 6, dq = e4 & 63;
            *(float4*)&Ks[r][dq * 4] = *(const float4*)&kk_[base + (size_t)(kt * 16 + r) * H_ + dq * 4];
            *(float4*)&Vs[r][dq * 4] = *(const float4*)&v  [base + (size_t)(kt * 16 + r) * H_ + dq * 4];
        }
        __syncthreads();
        float s = 0.f;
#pragma unroll 16
        for (int d = 0; d < 256; d += 4) {
            float4 qv = *(const float4*)&Qs[ty][d];
            float4 kv = *(const float4*)&Ks[tx][d];
            s = fmaf(qv.x, kv.x, fmaf(qv.y, kv.y, fmaf(qv.z, kv.z, fmaf(qv.w, kv.w, s))));
        }
        if (mrow == 0.f) s = 0.f;   // masked query row -> uniform softmax
        Ss[ty][tx] = s;
        __syncthreads();
        float tmax = -1e30f;
#pragma unroll
        for (int x = 0; x < 16; ++x) tmax = fmaxf(tmax, Ss[ty][x]);
        float mnew = fmaxf(m, tmax);
        float rsc = __expf(m - mnew);
        float wv[16], wsum = 0.f;
#pragma unroll
        for (int x = 0; x < 16; ++x) { wv[x] = __expf(Ss[ty][x] - mnew); wsum += wv[x]; }
        l = l * rsc + wsum; m = mnew;
#pragma unroll
        for (int dd = 0; dd < 16; ++dd) acc[dd] *= rsc;
#pragma unroll
        for (int x = 0; x < 16; ++x) {
            float wx = wv[x];
#pragma unroll
            for (int dd = 0; dd < 16; ++dd)
                acc[dd] = fmaf(wx, Vs[x][tx + dd * 16], acc[dd]);
        }
        __syncthreads();
    }
    float inv = 1.f / l;
#pragma unroll
    for (int dd = 0; dd < 16; ++dd)
        o[base + (size_t)(q0 + ty) * H_ + tx + dd * 16] = acc[dd] * inv;
}

// ---------------- FC1 split-K partials ----------------
__global__ __launch_bounds__(256) void k_fc1(
    const float* __restrict__ flat, const float* __restrict__ W1, float* __restrict__ part)
{
    __shared__ __align__(16) float Wt[100][260];
    __shared__ __align__(16) float fs[2][256];
    const int kc = blockIdx.x, tid = threadIdx.x;
    for (int e = tid; e < 25600; e += 256) {
        int k = e / 100, j = e - k * 100;
        Wt[j][k] = W1[(size_t)(kc * 256 + k) * 100 + j];
    }
    __syncthreads();
    const int bh = tid / 100, j = tid - bh * 100;
    for (int bb = 0; bb < 64; ++bb) {
        for (int e = tid; e < 512; e += 256) {
            int bi = e >> 8, k = e & 255;
            fs[bi][k] = flat[(size_t)(bb * 2 + bi) * 65536 + kc * 256 + k];
        }
        __syncthreads();
        if (bh < 2) {
            float acc = 0.f;
#pragma unroll 16
            for (int k = 0; k < 256; k += 4) {
                float4 fv = *(const float4*)&fs[bh][k];
                float4 wv = *(const float4*)&Wt[j][k];
                acc = fmaf(fv.x, wv.x, fmaf(fv.y, wv.y, fmaf(fv.z, wv.z, fmaf(fv.w, wv.w, acc))));
            }
            part[(size_t)kc * 12800 + (bb * 2 + bh) * 100 + j] = acc;
        }
        __syncthreads();
    }
}

// ---------------- head ----------------
__global__ __launch_bounds__(128) void k_head(
    const float* __restrict__ part, const float* __restrict__ b1,
    const float* __restrict__ W2, const float* __restrict__ b2, float* __restrict__ out)
{
    __shared__ float h1s[100];
    __shared__ float ls[2];
    const int b = blockIdx.x, tid = threadIdx.x;
    if (tid < 100) {
        float s = 0.f;
        for (int kc = 0; kc < 256; ++kc) s += part[(size_t)kc * 12800 + b * 100 + tid];
        s += b1[tid];
        h1s[tid] = fmaxf(s, 0.f);
    }
    __syncthreads();
    if (tid < 2) {
        float lg = b2[tid];
        for (int j = 0; j < 100; ++j) lg = fmaf(h1s[j], W2[j * 2 + tid], lg);
        ls[tid] = lg;
    }
    __syncthreads();
    if (tid == 0) {
        float mm = fmaxf(ls[0], ls[1]);
        float e0 = __expf(ls[0] - mm), e1 = __expf(ls[1] - mm);
        float inv = 1.f / (e0 + e1);
        out[b * 2 + 0] = e0 * inv;
        out[b * 2 + 1] = e1 * inv;
    }
}

// ---------------- launch ----------------
extern "C" void kernel_launch(void* const* d_in, const int* in_sizes, int n_in,
                              void* d_out, int out_size, void* d_ws, size_t ws_size,
                              hipStream_t stream) {
    (void)in_sizes; (void)n_in; (void)out_size; (void)ws_size;
    const int*   tokens = (const int*)  d_in[0];
    const void*  mask   =               d_in[1];
    const float* emb    = (const float*)d_in[2];
    const float* Wi     = (const float*)d_in[3];
    const float* Wh     = (const float*)d_in[4];
    const float* b_lstm = (const float*)d_in[5];
    const float* Wq     = (const float*)d_in[6];
    const float* bq     = (const float*)d_in[7];
    const float* Wk     = (const float*)d_in[8];
    const float* bk     = (const float*)d_in[9];
    const float* Wv     = (const float*)d_in[10];
    const float* bv     = (const float*)d_in[11];
    const float* Wo     = (const float*)d_in[12];
    const float* bo     = (const float*)d_in[13];
    const float* W1     = (const float*)d_in[14];
    const float* b1     = (const float*)d_in[15];
    const float* W2     = (const float*)d_in[16];
    const float* b2     = (const float*)d_in[17];
    float* out = (float*)d_out;

    float* ws = (float*)d_ws;
    float* reg0  = ws;                        // 33,554,432 f region (134 MB)
    short* xwb   = (short*)reg0;              // bf16 xW [T][B][1024]
    float* hsb   = reg0 + 33554432;           // 8,388,608 f region: hs bf16, then attn fp32
    short* hsb16 = (short*)hsb;
    float* maskf = hsb + 8388608;             //     32,768 f
    int*   rowtok= (int*)(maskf + 32768);     //     32,768 i
    int*   flag  = rowtok + 32768;            //          1 i
    short* whp   = (short*)((((uintptr_t)(flag + 1)) + 255) & ~(uintptr_t)255);
    short* wip   = whp + 262144;              // Wi pack: 640 frags = 327,680 shorts
    short* wqp   = wip + 327680;              // 128 frags = 65,536 shorts
    short* wkp   = wqp + 65536;
    short* wvp   = wkp + 65536;
    short* wop   = wvp + 65536;
    // region reuse inside reg0 after LSTM (xwb dead then):
    float* qb   = reg0;                       // q fp32
    float* kb   = reg0 + 8388608;             // k fp32 (later: fc1 partials)
    float* vb   = reg0 + 16777216;            // v fp32
    float* proj = reg0 + 25165824;            // attn @ Wo (= "flat") fp32
    float* attnf = hsb;                       // attention output fp32 (over hs region)
    float* part = kb;

    // prep
    hipMemsetAsync(flag, 0, sizeof(int), stream);
    k_detect<<<128, 256, 0, stream>>>((const unsigned char*)mask, flag);
    k_prep<<<128, 256, 0, stream>>>(mask, tokens, flag, maskf, rowtok);

    // weight packs (bf16 MFMA B-fragments)
    k_bpack<<<512, 64, 0, stream>>>(Wh, whp, 1024, 8, 256);
    k_bpack<<<640, 64, 0, stream>>>(Wi, wip, 1024, 10, 300);
    k_bpack<<<128, 64, 0, stream>>>(Wq, wqp, 256, 8, 256);
    k_bpack<<<128, 64, 0, stream>>>(Wk, wkp, 256, 8, 256);
    k_bpack<<<128, 64, 0, stream>>>(Wv, wvp, 256, 8, 256);
    k_bpack<<<128, 64, 0, stream>>>(Wo, wop, 256, 8, 256);

    // xW = gather(emb, tokens) @ Wi + b_lstm -> bf16  (M=32768, K=300(pad320), N=1024)
    k_gemm_mfma<true, false, true, 10><<<512, 256, 0, stream>>>(
        emb, wip, b_lstm, xwb, 1024, 300, rowtok, 1.f);

    // LSTM — MFMA, 8 blocks x 16 batch rows, 8 waves; hs out bf16
    lstm_mfma<<<8, 512, 0, stream>>>(xwb, whp, hsb16);

    // q,k,v projections from bf16 hs (q scaled by 1/16)
    k_gemm_mfma<false, true, false, 8><<<512, 256, 0, stream>>>(
        hsb16, wqp, bq, qb, 256, 256, nullptr, 0.0625f);
    k_gemm_mfma<false, true, false, 8><<<512, 256, 0, stream>>>(
        hsb16, wkp, bk, kb, 256, 256, nullptr, 1.f);
    k_gemm_mfma<false, true, false, 8><<<512, 256, 0, stream>>>(
        hsb16, wvp, bv, vb, 256, 256, nullptr, 1.f);

    // attention (writes fp32 over hs region; hs dead after qkv)
    k_attn<<<dim3(16, 128), 256, 0, stream>>>(qb, kb, vb, maskf, attnf);

    // output projection: proj = attn @ Wo + bo (fp32 A, fp32 out)
    k_gemm_mfma<false, false, false, 8><<<512, 256, 0, stream>>>(
        attnf, wop, bo, proj, 256, 256, nullptr, 1.f);

    // FC1 split-K partials + head
    k_fc1<<<256, 256, 0, stream>>>(proj, W1, part);
    k_head<<<128, 128, 0, stream>>>(part, b1, W2, b2, out);
}

// Round 8
// 2181.945 us; speedup vs baseline: 1.2651x; 1.0047x over previous
//
#include <hip/hip_runtime.h>
#include <stdint.h>

// Problem constants
#define B_   128
#define T_   256
#define H_   256
#define E_   300
#define G4_  1024   // 4*H

typedef __attribute__((ext_vector_type(8))) short bf16x8s;  // 8 bf16 (4 VGPRs)
typedef __attribute__((ext_vector_type(4))) float f32x4;

__device__ __forceinline__ short f2bf(float f) {
    unsigned u = __builtin_bit_cast(unsigned, f);
    unsigned r = (u + 0x7fffu + ((u >> 16) & 1u)) >> 16;   // RNE
    return (short)r;
}
__device__ __forceinline__ float bf2f(short s) {
    unsigned u = (unsigned)(unsigned short)s;
    return __builtin_bit_cast(float, u << 16);
}
__device__ __forceinline__ float sigm(float x) { return 1.f / (1.f + __expf(-x)); }
__device__ __forceinline__ float ftanh(float x) {
    float e = __expf(-2.f * x);
    return (1.f - e) / (1.f + e);
}

// ---------------- prep: mask dtype detection + mask/rowtok build ----------------
__global__ void k_detect(const unsigned char* __restrict__ m8, int* __restrict__ flag) {
    int i = blockIdx.x * 256 + threadIdx.x;      // 0..32767
    if ((i & 3) != 0 && m8[i] != 0) atomicOr(flag, 1);   // nonzero off-aligned byte => 1-byte bool layout
}

__global__ void k_prep(const void* __restrict__ mask, const int* __restrict__ tokens,
                       const int* __restrict__ flag, float* __restrict__ maskf,
                       int* __restrict__ rowtok) {
    int i = blockIdx.x * 256 + threadIdx.x;      // i = b*T + t
    int isbyte = *flag;
    int mv = isbyte ? (int)((const unsigned char*)mask)[i] : ((const int*)mask)[i];
    maskf[i] = mv ? 1.f : 0.f;                   // [b][t]
    int b = i >> 8, t = i & 255;
    rowtok[t * B_ + b] = tokens[i];              // row r = t*B + b  -> token
}

// ---------------- generic W[KREAL][N] -> packed bf16 MFMA B-fragments ----------------
// frag(nt, ks): lane l, elem i = W[ks*32 + (l>>4)*8 + i][nt*16 + (l&15)]  (0 if k>=KREAL)
__global__ void k_bpack(const float* __restrict__ W, short* __restrict__ out,
                        int N, int KS, int KREAL) {
    int frag = blockIdx.x;
    int nt = frag / KS, ks = frag - nt * KS;
    int l = threadIdx.x;
    int col = nt * 16 + (l & 15);
    int k0 = ks * 32 + (l >> 4) * 8;
    short tmp[8];
#pragma unroll
    for (int i = 0; i < 8; ++i) {
        int k = k0 + i;
        tmp[i] = (k < KREAL) ? f2bf(W[(size_t)k * N + col]) : (short)0;
    }
    int4 v;
    __builtin_memcpy(&v, tmp, 16);
    ((int4*)out)[(size_t)frag * 64 + l] = v;
}

// ---------------- bf16 MFMA GEMM: C = (A@B + bias) * scale ----------------
// OUTMODE: 0 = fp32 row-major, 1 = bf16 row-major, 2 = LSTM xW-fragment layout
//   (mode 2 assumes M = T*128 row order t*128+b, N=1024, 64-row blocks)
template<bool GATHER, bool ABF16, int OUTMODE, int KS>
__global__ __launch_bounds__(256) void k_gemm_mfma(
    const void* __restrict__ Av, const short* __restrict__ Bp,
    const float* __restrict__ bias, void* __restrict__ Cv,
    int N, int KREAL, const int* __restrict__ rowidx, float scale)
{
    constexpr int KP = KS * 32;
    constexpr int LDA = KP + 8;
    __shared__ __align__(16) short As[64 * LDA];
    const int tid = threadIdx.x;
    const int l = tid & 63, w = tid >> 6;
    const int cl = l & 15, rowq = l >> 4;
    const int m0 = blockIdx.x * 64;

    for (int e = tid; e < 64 * KP; e += 256) {
        int r = e / KP, k = e - r * KP;
        int row = m0 + r;
        int arow = GATHER ? rowidx[row] : row;
        short sv = 0;
        if (k < KREAL) {
            if constexpr (ABF16) sv = ((const short*)Av)[(size_t)arow * KREAL + k];
            else                 sv = f2bf(((const float*)Av)[(size_t)arow * KREAL + k]);
        }
        As[r * LDA + k] = sv;
    }
    __syncthreads();

    bf16x8s a[KS];
#pragma unroll
    for (int ks = 0; ks < KS; ++ks)
        a[ks] = *(const bf16x8s*)&As[(w * 16 + cl) * LDA + ks * 32 + rowq * 8];

    const int nchunks = N >> 8;
    for (int ch = 0; ch < nchunks; ++ch) {
#pragma unroll
        for (int ntl = 0; ntl < 16; ++ntl) {
            const int nt = ch * 16 + ntl;
            const float bv = bias[nt * 16 + cl];
            f32x4 y = {bv, bv, bv, bv};
#pragma unroll
            for (int ks = 0; ks < KS; ++ks) {
                bf16x8s bf = *(const bf16x8s*)&Bp[((size_t)(nt * KS + ks) * 64 + l) * 8];
                y = __builtin_amdgcn_mfma_f32_16x16x32_bf16(a[ks], bf, y, 0, 0, 0);
            }
            if constexpr (OUTMODE == 2) {
                // verified mapping: GEMM lane l == LSTM lane l; r contiguous
                const int t  = m0 >> 7;
                const int bb = ((m0 & 127) >> 4) + w;
                const int wl = (nt >> 1) & 7, pp = nt & 1, gg = nt >> 4;
                const size_t fi = ((((size_t)t * 8 + bb) * 8 + wl) * 2 + pp) * 4 + gg;
                short4 o;
                o.x = f2bf(y[0] * scale); o.y = f2bf(y[1] * scale);
                o.z = f2bf(y[2] * scale); o.w = f2bf(y[3] * scale);
                *(short4*)&((short*)Cv)[fi * 256 + l * 4] = o;
            } else {
#pragma unroll
                for (int r = 0; r < 4; ++r) {
                    size_t idx = (size_t)(m0 + w * 16 + rowq * 4 + r) * N + nt * 16 + cl;
                    float ov = y[r] * scale;
                    if constexpr (OUTMODE == 1) ((short*)Cv)[idx] = f2bf(ov);
                    else                        ((float*)Cv)[idx] = ov;
                }
            }
        }
    }
}

// ---------------- MFMA LSTM: 8 blocks x 16 batch rows, 8 waves (2/SIMD) ----------------
// Wave w owns hidden units [32w, 32w+32): n-tiles {g*16 + 2w + p}, g=gate, p=0,1.
// Wh: ks2-5 in regs, ks0-1 in LDS, ks6-7 L2-streamed. xW in fragment layout, prefetched 1 step.
#define LDA_H 264

__global__ __launch_bounds__(512, 2) void lstm_mfma(
    const short* __restrict__ xwp, const short* __restrict__ whp,
    short* __restrict__ hs)
{
    __shared__ __align__(16) short whc[128 * 64 * 8];     // frags (nt, ks<2): 128 KB
    __shared__ __align__(16) short hb[2][16 * LDA_H];
    const int tid = threadIdx.x;
    const int l = tid & 63;
    const int w = tid >> 6;            // wave 0..7
    const int cl = l & 15;
    const int rowq = l >> 4;
    const int bb = blockIdx.x;
    const int bbase = bb * 16;

    for (int e = tid; e < 128 * 64; e += 512) {
        int frag = e >> 6, q = e & 63;
        int nt = frag >> 1, ks = frag & 1;
        ((int4*)whc)[e] = ((const int4*)whp)[(nt * 8 + ks) * 64 + q];
    }
    for (int e = tid; e < 2 * 16 * LDA_H; e += 512) ((short*)hb)[e] = 0;

    bf16x8s wreg[2][4][4];   // ks 2..5
#pragma unroll
    for (int p = 0; p < 2; ++p)
#pragma unroll
        for (int g = 0; g < 4; ++g)
#pragma unroll
            for (int kr = 0; kr < 4; ++kr) {
                const int nt = g * 16 + w * 2 + p;
                wreg[p][g][kr] = *(const bf16x8s*)&whp[((size_t)(nt * 8 + 2 + kr) * 64 + l) * 8];
            }

    float creg[2][4];
#pragma unroll
    for (int p = 0; p < 2; ++p)
#pragma unroll
        for (int r = 0; r < 4; ++r) creg[p][r] = 0.f;

    // xW fragment base for (t,p,g): fi = (((t*8+bb)*8+w)*2+p)*4+g, 256 shorts/frag
    const short* xbase = xwp + ((size_t)bb * 8 + w) * 2 * 4 * 256 + (size_t)l * 4;
    const size_t tstride = (size_t)8 * 8 * 2 * 4 * 256;   // per-t stride in shorts

    auto ld_xw = [&](int t, short4 (&dst)[2][4]) {
        const short* p0 = xbase + (size_t)t * tstride;
#pragma unroll
        for (int p = 0; p < 2; ++p)
#pragma unroll
            for (int g = 0; g < 4; ++g)
                dst[p][g] = *(const short4*)&p0[(p * 4 + g) * 256];
    };

    short4 xwA[2][4], xwB[2][4];
    ld_xw(0, xwA);
    __syncthreads();

    auto step = [&](int t, short4 (&cur)[2][4], short4 (&nxt)[2][4]) {
        // prefetch next step's xW first (independent of recurrence)
        ld_xw(t + 1, nxt);

        const short* hbr = hb[t & 1];
        short* hbw = hb[(t + 1) & 1];
        bf16x8s a[8];
#pragma unroll
        for (int ks = 0; ks < 8; ++ks)
            a[ks] = *(const bf16x8s*)&hbr[cl * LDA_H + ks * 32 + rowq * 8];

        f32x4 y[2][4];
#pragma unroll
        for (int p = 0; p < 2; ++p)
#pragma unroll
            for (int g = 0; g < 4; ++g) {
                y[p][g][0] = bf2f(cur[p][g].x);
                y[p][g][1] = bf2f(cur[p][g].y);
                y[p][g][2] = bf2f(cur[p][g].z);
                y[p][g][3] = bf2f(cur[p][g].w);
            }

#pragma unroll
        for (int p = 0; p < 2; ++p) {
#pragma unroll
            for (int g = 0; g < 4; ++g) {
                const int nt = g * 16 + w * 2 + p;
                const size_t sb = ((size_t)nt * 8 * 64 + l) * 8;
                bf16x8s s6 = *(const bf16x8s*)&whp[sb + 6 * 64 * 8];
                bf16x8s s7 = *(const bf16x8s*)&whp[sb + 7 * 64 * 8];
                bf16x8s c0 = *(const bf16x8s*)&whc[((nt * 2 + 0) * 64 + l) * 8];
                bf16x8s c1 = *(const bf16x8s*)&whc[((nt * 2 + 1) * 64 + l) * 8];
                y[p][g] = __builtin_amdgcn_mfma_f32_16x16x32_bf16(a[2], wreg[p][g][0], y[p][g], 0, 0, 0);
                y[p][g] = __builtin_amdgcn_mfma_f32_16x16x32_bf16(a[3], wreg[p][g][1], y[p][g], 0, 0, 0);
                y[p][g] = __builtin_amdgcn_mfma_f32_16x16x32_bf16(a[4], wreg[p][g][2], y[p][g], 0, 0, 0);
                y[p][g] = __builtin_amdgcn_mfma_f32_16x16x32_bf16(a[5], wreg[p][g][3], y[p][g], 0, 0, 0);
                y[p][g] = __builtin_amdgcn_mfma_f32_16x16x32_bf16(a[0], c0, y[p][g], 0, 0, 0);
                y[p][g] = __builtin_amdgcn_mfma_f32_16x16x32_bf16(a[1], c1, y[p][g], 0, 0, 0);
                y[p][g] = __builtin_amdgcn_mfma_f32_16x16x32_bf16(a[6], s6, y[p][g], 0, 0, 0);
                y[p][g] = __builtin_amdgcn_mfma_f32_16x16x32_bf16(a[7], s7, y[p][g], 0, 0, 0);
            }
        }

#pragma unroll
        for (int p = 0; p < 2; ++p) {
            const int j = w * 32 + p * 16 + cl;
#pragma unroll
            for (int r = 0; r < 4; ++r) {
                float iv = sigm(y[p][0][r]);
                float fv = sigm(y[p][1][r]);
                float gv = ftanh(y[p][2][r]);
                float ov = sigm(y[p][3][r]);
                float c = fmaf(fv, creg[p][r], iv * gv);
                creg[p][r] = c;
                float hv = ov * ftanh(c);
                short hvb = f2bf(hv);
                int b = rowq * 4 + r;
                hbw[b * LDA_H + j] = hvb;
                hs[((size_t)(bbase + b) * T_ + t) * H_ + j] = hvb;
            }
        }
        __syncthreads();
    };

    for (int t = 0; t < T_; t += 2) {
        step(t,     xwA, xwB);
        step(t + 1, xwB, xwA);   // prefetches t+2; t=256 read lands in slack pad
    }
}

// ---------------- flash-style single-head attention (fp32 q,k,v) ----------------
__global__ __launch_bounds__(256) void k_attn(
    const float* __restrict__ q, const float* __restrict__ kk_,
    const float* __restrict__ v, const float* __restrict__ maskf,
    float* __restrict__ o)
{
    __shared__ __align__(16) float Qs[16][260];
    __shared__ __align__(16) float Ks[16][260];
    __shared__ __align__(16) float Vs[16][260];
    __shared__ float Ss[16][16];
    const int tid = threadIdx.x;
    const int tx = tid & 15, ty = tid >> 4;
    const int b = blockIdx.y, q0 = blockIdx.x * 16;
    const size_t base = (size_t)b * T_ * H_;

    for (int e4 = tid; e4 < 1024; e4 += 256) {
        int r = e4 >> 6, dq = e4 & 63;
        *(float4*)&Qs[r][dq * 4] = *(const float4*)&q[base + (size_t)(q0 + r) * H_ + dq * 4];
    }
    const float mrow = maskf[b * T_ + q0 + ty];
    float m = -1e30f, l = 0.f;
    float acc[16];
#pragma unroll
    for (int i = 0; i < 16; ++i) acc[i] = 0.f;

    for (int kt = 0; kt < 16; ++kt) {
        for (int e4 = tid; e4 < 1024; e4 += 256) {
            int r = e4 >> 6, dq = e4 & 63;
            *(float4*)&Ks[r][dq * 4] = *(const float4*)&kk_[base + (size_t)(kt * 16 + r) * H_ + dq * 4];
            *(float4*)&Vs[r][dq * 4] = *(const float4*)&v  [base + (size_t)(kt * 16 + r) * H_ + dq * 4];
        }
        __syncthreads();
        float s = 0.f;
#pragma unroll 16
        for (int d = 0; d < 256; d += 4) {
            float4 qv = *(const float4*)&Qs[ty][d];
            float4 kv = *(const float4*)&Ks[tx][d];
            s = fmaf(qv.x, kv.x, fmaf(qv.y, kv.y, fmaf(qv.z, kv.z, fmaf(qv.w, kv.w, s))));
        }
        if (mrow == 0.f) s = 0.f;   // masked query row -> uniform softmax
        Ss[ty][tx] = s;
        __syncthreads();
        float tmax = -1e30f;
#pragma unroll
        for (int x = 0; x < 16; ++x) tmax = fmaxf(tmax, Ss[ty][x]);
        float mnew = fmaxf(m, tmax);
        float rsc = __expf(m - mnew);
        float wv[16], wsum = 0.f;
#pragma unroll
        for (int x = 0; x < 16; ++x) { wv[x] = __expf(Ss[ty][x] - mnew); wsum += wv[x]; }
        l = l * rsc + wsum; m = mnew;
#pragma unroll
        for (int dd = 0; dd < 16; ++dd) acc[dd] *= rsc;
#pragma unroll
        for (int x = 0; x < 16; ++x) {
            float wx = wv[x];
#pragma unroll
            for (int dd = 0; dd < 16; ++dd)
                acc[dd] = fmaf(wx, Vs[x][tx + dd * 16], acc[dd]);
        }
        __syncthreads();
    }
    float inv = 1.f / l;
#pragma unroll
    for (int dd = 0; dd < 16; ++dd)
        o[base + (size_t)(q0 + ty) * H_ + tx + dd * 16] = acc[dd] * inv;
}

// ---------------- FC1 split-K partials ----------------
__global__ __launch_bounds__(256) void k_fc1(
    const float* __restrict__ flat, const float* __restrict__ W1, float* __restrict__ part)
{
    __shared__ __align__(16) float Wt[100][260];
    __shared__ __align__(16) float fs[2][256];
    const int kc = blockIdx.x, tid = threadIdx.x;
    for (int e = tid; e < 25600; e += 256) {
        int k = e / 100, j = e - k * 100;
        Wt[j][k] = W1[(size_t)(kc * 256 + k) * 100 + j];
    }
    __syncthreads();
    const int bh = tid / 100, j = tid - bh * 100;
    for (int bb = 0; bb < 64; ++bb) {
        for (int e = tid; e < 512; e += 256) {
            int bi = e >> 8, k = e & 255;
            fs[bi][k] = flat[(size_t)(bb * 2 + bi) * 65536 + kc * 256 + k];
        }
        __syncthreads();
        if (bh < 2) {
            float acc = 0.f;
#pragma unroll 16
            for (int k = 0; k < 256; k += 4) {
                float4 fv = *(const float4*)&fs[bh][k];
                float4 wv = *(const float4*)&Wt[j][k];
                acc = fmaf(fv.x, wv.x, fmaf(fv.y, wv.y, fmaf(fv.z, wv.z, fmaf(fv.w, wv.w, acc))));
            }
            part[(size_t)kc * 12800 + (bb * 2 + bh) * 100 + j] = acc;
        }
        __syncthreads();
    }
}

// ---------------- head ----------------
__global__ __launch_bounds__(128) void k_head(
    const float* __restrict__ part, const float* __restrict__ b1,
    const float* __restrict__ W2, const float* __restrict__ b2, float* __restrict__ out)
{
    __shared__ float h1s[100];
    __shared__ float ls[2];
    const int b = blockIdx.x, tid = threadIdx.x;
    if (tid < 100) {
        float s = 0.f;
        for (int kc = 0; kc < 256; ++kc) s += part[(size_t)kc * 12800 + b * 100 + tid];
        s += b1[tid];
        h1s[tid] = fmaxf(s, 0.f);
    }
    __syncthreads();
    if (tid < 2) {
        float lg = b2[tid];
        for (int j = 0; j < 100; ++j) lg = fmaf(h1s[j], W2[j * 2 + tid], lg);
        ls[tid] = lg;
    }
    __syncthreads();
    if (tid == 0) {
        float mm = fmaxf(ls[0], ls[1]);
        float e0 = __expf(ls[0] - mm), e1 = __expf(ls[1] - mm);
        float inv = 1.f / (e0 + e1);
        out[b * 2 + 0] = e0 * inv;
        out[b * 2 + 1] = e1 * inv;
    }
}

// ---------------- launch ----------------
extern "C" void kernel_launch(void* const* d_in, const int* in_sizes, int n_in,
                              void* d_out, int out_size, void* d_ws, size_t ws_size,
                              hipStream_t stream) {
    (void)in_sizes; (void)n_in; (void)out_size; (void)ws_size;
    const int*   tokens = (const int*)  d_in[0];
    const void*  mask   =               d_in[1];
    const float* emb    = (const float*)d_in[2];
    const float* Wi     = (const float*)d_in[3];
    const float* Wh     = (const float*)d_in[4];
    const float* b_lstm = (const float*)d_in[5];
    const float* Wq     = (const float*)d_in[6];
    const float* bq     = (const float*)d_in[7];
    const float* Wk     = (const float*)d_in[8];
    const float* bk     = (const float*)d_in[9];
    const float* Wv     = (const float*)d_in[10];
    const float* bv     = (const float*)d_in[11];
    const float* Wo     = (const float*)d_in[12];
    const float* bo     = (const float*)d_in[13];
    const float* W1     = (const float*)d_in[14];
    const float* b1     = (const float*)d_in[15];
    const float* W2     = (const float*)d_in[16];
    const float* b2     = (const float*)d_in[17];
    float* out = (float*)d_out;

    float* ws = (float*)d_ws;
    float* reg0  = ws;                        // 33,554,432 f region (134 MB)
    short* xwp   = (short*)reg0;              // bf16 xW frag layout: 33,554,432 + 131,072 slack shorts
    float* hsb   = reg0 + 33554432;           // 8,388,608 f region: hs bf16, then attn fp32
    short* hsb16 = (short*)hsb;
    float* maskf = hsb + 8388608;             //     32,768 f
    int*   rowtok= (int*)(maskf + 32768);     //     32,768 i
    int*   flag  = rowtok + 32768;            //          1 i
    short* whp   = (short*)((((uintptr_t)(flag + 1)) + 255) & ~(uintptr_t)255);
    short* wip   = whp + 262144;              // Wi pack: 640 frags
    short* wqp   = wip + 327680;
    short* wkp   = wqp + 65536;
    short* wvp   = wkp + 65536;
    short* wop   = wvp + 65536;
    // region reuse inside reg0 after LSTM (xwp dead then):
    float* qb   = reg0;
    float* kb   = reg0 + 8388608;
    float* vb   = reg0 + 16777216;
    float* proj = reg0 + 25165824;
    float* attnf = hsb;
    float* part = kb;

    // prep
    hipMemsetAsync(flag, 0, sizeof(int), stream);
    k_detect<<<128, 256, 0, stream>>>((const unsigned char*)mask, flag);
    k_prep<<<128, 256, 0, stream>>>(mask, tokens, flag, maskf, rowtok);

    // weight packs
    k_bpack<<<512, 64, 0, stream>>>(Wh, whp, 1024, 8, 256);
    k_bpack<<<640, 64, 0, stream>>>(Wi, wip, 1024, 10, 300);
    k_bpack<<<128, 64, 0, stream>>>(Wq, wqp, 256, 8, 256);
    k_bpack<<<128, 64, 0, stream>>>(Wk, wkp, 256, 8, 256);
    k_bpack<<<128, 64, 0, stream>>>(Wv, wvp, 256, 8, 256);
    k_bpack<<<128, 64, 0, stream>>>(Wo, wop, 256, 8, 256);

    // xW = gather(emb,tokens) @ Wi + b_lstm -> bf16 in LSTM fragment layout
    k_gemm_mfma<true, false, 2, 10><<<512, 256, 0, stream>>>(
        emb, wip, b_lstm, xwp, 1024, 300, rowtok, 1.f);

    // LSTM — MFMA, 8 blocks x 16 batch rows, 8 waves, xW prefetched 1 step ahead
    lstm_mfma<<<8, 512, 0, stream>>>(xwp, whp, hsb16);

    // q,k,v projections from bf16 hs (q scaled by 1/16)
    k_gemm_mfma<false, true, 0, 8><<<512, 256, 0, stream>>>(
        hsb16, wqp, bq, qb, 256, 256, nullptr, 0.0625f);
    k_gemm_mfma<false, true, 0, 8><<<512, 256, 0, stream>>>(
        hsb16, wkp, bk, kb, 256, 256, nullptr, 1.f);
    k_gemm_mfma<false, true, 0, 8><<<512, 256, 0, stream>>>(
        hsb16, wvp, bv, vb, 256, 256, nullptr, 1.f);

    // attention (writes fp32 over hs region)
    k_attn<<<dim3(16, 128), 256, 0, stream>>>(qb, kb, vb, maskf, attnf);

    // output projection
    k_gemm_mfma<false, false, 0, 8><<<512, 256, 0, stream>>>(
        attnf, wop, bo, proj, 256, 256, nullptr, 1.f);

    // FC1 split-K partials + head
    k_fc1<<<256, 256, 0, stream>>>(proj, W1, part);
    k_head<<<128, 128, 0, stream>>>(part, b1, W2, b2, out);
}